// Round 5
// baseline (174.757 us; speedup 1.0000x reference)
//
#include <hip/hip_runtime.h>
#include <math.h>

#define INV_B (1.0f / 8192.0f)

typedef float  v2f  __attribute__((ext_vector_type(2)));
typedef _Float16 half8 __attribute__((ext_vector_type(8)));
typedef float  f32x4 __attribute__((ext_vector_type(4)));
typedef unsigned u32x4 __attribute__((ext_vector_type(4)));

// ---------------------------------------------------------------------------
// Compile-time GF(2) tracking of the CNOT network (R3-verified, absmax 0.0).
// Index i (8 bits): wire w <-> bit (7-w).  Storage: i = 4*lane + reg.
// ---------------------------------------------------------------------------
struct QTables {
    int xm[6][8];   // xor (partner) mask per (layer, wire)
    int rm[6][8];   // row parity mask per (layer, wire)
    int meas[4];    // measurement parity masks on storage index, wires 0..3
};
constexpr QTables make_tables() {
    QTables T{};
    int Mrow[8] = {}, Ncol[8] = {};
    for (int b = 0; b < 8; ++b) { Mrow[b] = 1 << b; Ncol[b] = 1 << b; }
    constexpr int bc[11] = {7,6,5,4,3,2,1,0,7,5,3};
    constexpr int bt[11] = {6,5,4,3,2,1,0,7,5,3,1};
    for (int l = 0; l < 6; ++l) {
        for (int w = 0; w < 8; ++w) { T.xm[l][w] = Ncol[7 - w]; T.rm[l][w] = Mrow[7 - w]; }
        for (int k = 0; k < 11; ++k) { Mrow[bt[k]] ^= Mrow[bc[k]]; Ncol[bc[k]] ^= Ncol[bt[k]]; }
    }
    for (int w = 0; w < 4; ++w) T.meas[w] = Mrow[7 - w];
    return T;
}
constexpr QTables TB = make_tables();

// xor-shuffle along lane mask ML: 1..3 DPP quad_perm (VALU pipe),
// 4..31 ds_swizzle (LDS pipe, immediate offset), >=32 shfl (bpermute).
template<int ML>
static __device__ __forceinline__ float lanex(float v) {
    if constexpr (ML == 0) { return v; }
    else if constexpr (ML == 1) { return __int_as_float(__builtin_amdgcn_update_dpp(0, __float_as_int(v), 0xB1, 0xF, 0xF, true)); }
    else if constexpr (ML == 2) { return __int_as_float(__builtin_amdgcn_update_dpp(0, __float_as_int(v), 0x4E, 0xF, 0xF, true)); }
    else if constexpr (ML == 3) { return __int_as_float(__builtin_amdgcn_update_dpp(0, __float_as_int(v), 0x1B, 0xF, 0xF, true)); }
    else if constexpr (ML < 32) { return __int_as_float(__builtin_amdgcn_ds_swizzle(__float_as_int(v), 0x1F | (ML << 10))); }
    else { return __shfl_xor(v, ML, 64); }
}

static __device__ __forceinline__ float tanh_fast(float v) {
    const float c = fminf(fmaxf(v, -10.f), 10.f);
    const float e = __expf(2.f * c);
    return (e - 1.f) / (e + 1.f);
}

// Coherent (agent-scope, L2-bypassing) helpers. All cross-block traffic goes
// through these => NO L2 fences (wbl2/inv) are needed anywhere.
static __device__ __forceinline__ void coh_store_h(_Float16* p, _Float16 v) {
    __hip_atomic_store((short*)p, __builtin_bit_cast(short, v),
                       __ATOMIC_RELAXED, __HIP_MEMORY_SCOPE_AGENT);
}
static __device__ __forceinline__ void coh_store_f(float* p, float v) {
    __hip_atomic_store(p, v, __ATOMIC_RELAXED, __HIP_MEMORY_SCOPE_AGENT);
}
static __device__ __forceinline__ float coh_load_f(const float* p) {
    return __hip_atomic_load(p, __ATOMIC_RELAXED, __HIP_MEMORY_SCOPE_AGENT);
}
static __device__ __forceinline__ half8 coh_load_h8(const _Float16* p) {
    const unsigned* q = (const unsigned*)p;
    u32x4 t;
    t[0] = __hip_atomic_load(q + 0, __ATOMIC_RELAXED, __HIP_MEMORY_SCOPE_AGENT);
    t[1] = __hip_atomic_load(q + 1, __ATOMIC_RELAXED, __HIP_MEMORY_SCOPE_AGENT);
    t[2] = __hip_atomic_load(q + 2, __ATOMIC_RELAXED, __HIP_MEMORY_SCOPE_AGENT);
    t[3] = __hip_atomic_load(q + 3, __ATOMIC_RELAXED, __HIP_MEMORY_SCOPE_AGENT);
    return __builtin_bit_cast(half8, t);
}

// Fused SU(2) gate, packed complex (R3/R5-verified math).
template<int XM, int RM>
static __device__ __forceinline__ void gate(v2f (&z)[4], const int lane,
                                            const float u00r, const float u00i,
                                            const float u01r, const float u01i) {
    constexpr int ML = XM >> 2, MR = XM & 3;
    constexpr int RL = RM >> 2, RR = RM & 3;
    const int pl = __popc(lane & RL) & 1;
    const float csi0 = pl ? -u00i : u00i;
    const float cpr0 = pl ? -u01r : u01r;
    const float csi1 = -csi0, cpr1 = -cpr0;
    v2f p[4];
    #pragma unroll
    for (int r = 0; r < 4; ++r) {
        p[r].x = lanex<ML>(z[r ^ MR].x);
        p[r].y = lanex<ML>(z[r ^ MR].y);
    }
    #pragma unroll
    for (int r = 0; r < 4; ++r) {
        const int pb = __builtin_popcount(r & RR) & 1;
        const float csi = pb ? csi1 : csi0;
        const float cpr = pb ? cpr1 : cpr0;
        const v2f zs = { -z[r].y, z[r].x };
        const v2f ps = { -p[r].y, p[r].x };
        z[r] = ((u00r * z[r] + csi * zs) + cpr * p[r]) + u01i * ps;
    }
}

// ---------------------------------------------------------------------------
// Fence-FREE grid barrier (256 blocks = 1/CU, co-residency proven R2-R4).
// All cross-block data is coherent (agent-scope ops at the device coherence
// point), so no L2 writeback/invalidate is needed: R3/R4's residual
// ~15us/barrier was the per-block wbl2+inv pair, not arrival mechanics.
// __syncthreads before arrival drains vmcnt (compiler-tracked atomics), so
// a block's coherent writes reach L3 before its arrival store.
// ---------------------------------------------------------------------------
static __device__ __forceinline__ void gbar(unsigned* arr, unsigned* rel) {
    __syncthreads();
    if (blockIdx.x == 0) {
        if (threadIdx.x != 0) {        // poll arrival slot of block threadIdx.x
            while (!__hip_atomic_load(&arr[threadIdx.x], __ATOMIC_RELAXED,
                                      __HIP_MEMORY_SCOPE_AGENT))
                __builtin_amdgcn_s_sleep(4);
        }
        __syncthreads();               // all arrivals seen
        if (threadIdx.x == 0)
            __hip_atomic_store(rel, 1u, __ATOMIC_RELAXED, __HIP_MEMORY_SCOPE_AGENT);
        __syncthreads();
    } else {
        if (threadIdx.x == 0) {
            __hip_atomic_store(&arr[blockIdx.x], 1u, __ATOMIC_RELAXED,
                               __HIP_MEMORY_SCOPE_AGENT);
            while (!__hip_atomic_load(rel, __ATOMIC_RELAXED, __HIP_MEMORY_SCOPE_AGENT))
                __builtin_amdgcn_s_sleep(4);
        }
        __syncthreads();
    }
}

#define XS 264   // padded LDS stride in halves (528B, 16B-divisible)

// ---------------------------------------------------------------------------
// Single fused kernel, 256 blocks x 256 threads (4 waves), 3 grid barriers.
// Phase A: stage x tile (32 rows) once; wave0 builds basis state k=blockIdx.x
//          of the circuit operator W; waves1-2 cf MLP (MFMA); wave3 zeroes.
// Phase B: ALL 4 waves run the quantum gemm: wave&1 = row tile, wave>>1 =
//          column half (c 0..7 / 8..15); partials combined via LDS atomics.
// Phase C: analytic BN1 + relu + layer2 -> z2 (LDS) + z2 stats atomics.
// Phase D: BN2 + relu + layer3 + layer4 + sigmoid -> out.
// All math verbatim from the R0/R3/R5-verified version.
// ---------------------------------------------------------------------------
__global__ __launch_bounds__(256) void k_fused(
        const float* __restrict__ x, const float* __restrict__ qw,
        const float* __restrict__ fW1, const float* __restrict__ fb1,
        const float* __restrict__ fW2, const float* __restrict__ fb2,
        const float* __restrict__ aW, const float* __restrict__ ab,
        const float* __restrict__ cW1, const float* __restrict__ cb1,
        const float* __restrict__ g1, const float* __restrict__ be1,
        const float* __restrict__ cW2, const float* __restrict__ cb2,
        const float* __restrict__ g2, const float* __restrict__ be2,
        const float* __restrict__ cW3, const float* __restrict__ cb3,
        const float* __restrict__ cW4, const float* __restrict__ cb4,
        _Float16* __restrict__ Wt, float* __restrict__ acc1,
        float* __restrict__ acc2, unsigned* __restrict__ bar,
        float* __restrict__ out)
{
    const int t = threadIdx.x, b = blockIdx.x;
    const int lane = t & 63, w = t >> 6;
    const int R0 = b * 32;

    __shared__ _Float16 xa[32 * XS];     // x tile, f16 (32 rows x 256)
    __shared__ float4 Us[48];            // per-gate SU(2) params
    __shared__ float cfb[32][4];         // cf (feature MLP output)
    __shared__ float hb[32][4];          // h
    __shared__ float z2b[32][16];        // z2
    __shared__ float pS[32];             // phase-B partial |amp|^2 sums
    __shared__ float pQ[4][32];          // phase-B partial signed sums
    __shared__ float sA[20];
    __shared__ float m1s[32], is1[32];
    __shared__ float sB[32];
    __shared__ float m2s[16], is2[16];

    // ======== Phase A ========
    // stage x rows R0..R0+31 as f16 (the ONLY x read for this block)
    #pragma unroll
    for (int i = 0; i < 8; ++i) {
        const int idx = i * 256 + t;
        const int row = idx >> 6, c4 = idx & 63;
        const float4 xv = ((const float4*)(x + (long)(R0 + row) * 256))[c4];
        _Float16* d = &xa[row * XS + c4 * 4];
        d[0] = (_Float16)xv.x; d[1] = (_Float16)xv.y;
        d[2] = (_Float16)xv.z; d[3] = (_Float16)xv.w;
    }
    if (t < 48) {
        const int l = t >> 3, q = t & 7;
        const float* a = qw + l * 24 + q * 3;
        const float h1 = 0.5f * a[0], h2 = 0.5f * a[1], h3 = 0.5f * a[2];
        const float c1 = cosf(h1), s1 = sinf(h1);
        const float c2 = cosf(h2), s2 = sinf(h2);
        const float c3 = cosf(h3), s3 = sinf(h3);
        const float m00r =  c1 * c2, m00i =  s1 * s2;   // (Ry*Rx) row 0
        const float m01r = -c1 * s2, m01i = -s1 * c2;
        float4 u;
        u.x = m00r * c3 + m00i * s3;  u.y = m00i * c3 - m00r * s3;  // u00 e^{-i h3}
        u.z = m01r * c3 + m01i * s3;  u.w = m01i * c3 - m01r * s3;  // u01 e^{-i h3}
        Us[t] = u;
    }
    if (t >= 192 && t < 224) {          // zero phase-B LDS partials
        const int r = t - 192;
        pS[r] = 0.f;
        pQ[0][r] = 0.f; pQ[1][r] = 0.f; pQ[2][r] = 0.f; pQ[3][r] = 0.f;
    }
    if (b < 32 && w == 3) {             // zero accumulator slots (coherent: ws poisoned)
        const int l = t - 192;
        if (l < 20) coh_store_f(&acc1[b * 20 + l], 0.f);
        if (l < 32) coh_store_f(&acc2[b * 32 + l], 0.f);
    }
    __syncthreads();

    if (w == 0) {
        // ---- quantum operator build: basis state k = blockIdx.x (fp32 exact)
        const int k = b;
        v2f z[4];
        #pragma unroll
        for (int r = 0; r < 4; ++r) {
            z[r].x = (4 * lane + r == k) ? 1.f : 0.f;
            z[r].y = 0.f;
        }
#define GATE(L, W) { const float4 u = Us[(L) * 8 + (W)]; \
                     gate<TB.xm[L][W], TB.rm[L][W]>(z, lane, u.x, u.y, u.z, u.w); }
#define LAYER(L) GATE(L,0) GATE(L,1) GATE(L,2) GATE(L,3) GATE(L,4) GATE(L,5) GATE(L,6) GATE(L,7)
        LAYER(0) LAYER(1) LAYER(2) LAYER(3) LAYER(4) LAYER(5)
#undef LAYER
#undef GATE
        #pragma unroll
        for (int r = 0; r < 4; ++r) {
            const int i = 4 * lane + r;            // storage index
            coh_store_h(&Wt[(long)i * 256 + k],         (_Float16)z[r].x);
            coh_store_h(&Wt[(long)(256 + i) * 256 + k], (_Float16)z[r].y);
        }
    } else if (w <= 2) {
        // ---- cf MLP for m-tile (w-1): rows mt*16..+15 (R5-verified math)
        const int g = lane >> 4, col = lane & 15;
        const int mt = w - 1;
        half8 bf[8];
        #pragma unroll
        for (int kb = 0; kb < 8; ++kb)
            bf[kb] = *(const half8*)&xa[(mt * 16 + col) * XS + kb * 32 + g * 8];
        float accc[4] = {0.f, 0.f, 0.f, 0.f};
        #pragma unroll
        for (int jc = 0; jc < 4; ++jc) {
            f32x4 cv = {0.f, 0.f, 0.f, 0.f};
            #pragma unroll
            for (int kb = 0; kb < 8; ++kb) {
                const float* ap = fW1 + (long)(jc * 16 + col) * 256 + kb * 32 + g * 8;
                const float4 a0 = *(const float4*)ap;
                const float4 a1v = *(const float4*)(ap + 4);
                half8 af;
                af[0] = (_Float16)a0.x;  af[1] = (_Float16)a0.y;
                af[2] = (_Float16)a0.z;  af[3] = (_Float16)a0.w;
                af[4] = (_Float16)a1v.x; af[5] = (_Float16)a1v.y;
                af[6] = (_Float16)a1v.z; af[7] = (_Float16)a1v.w;
                cv = __builtin_amdgcn_mfma_f32_16x16x32_f16(af, bf[kb], cv, 0, 0, 0);
            }
            #pragma unroll
            for (int r = 0; r < 4; ++r) {
                const int j = jc * 16 + g * 4 + r;
                const float z = fmaxf(cv[r] + fb1[j], 0.f);
                #pragma unroll
                for (int c = 0; c < 4; ++c) accc[c] += z * fW2[c * 64 + j];
            }
        }
        #pragma unroll
        for (int c = 0; c < 4; ++c) {
            accc[c] += __shfl_xor(accc[c], 16, 64);
            accc[c] += __shfl_xor(accc[c], 32, 64);
        }
        if (g == 0) {
            cfb[mt * 16 + col][0] = tanh_fast(accc[0] + fb2[0]);
            cfb[mt * 16 + col][1] = tanh_fast(accc[1] + fb2[1]);
            cfb[mt * 16 + col][2] = tanh_fast(accc[2] + fb2[2]);
            cfb[mt * 16 + col][3] = tanh_fast(accc[3] + fb2[3]);
        }
    }

    gbar(bar, bar + 832);

    // ======== Phase B: quantum gemm, ALL 4 waves (R5-verified frag maps) ====
    {
        const int col = lane & 15, quad = lane >> 4;
        const int wrow = w & 1;          // row tile (rows wrow*16..+15)
        const int whalf = w >> 1;        // column half (c = whalf*8 + cc)
        half8 af[8];
        #pragma unroll
        for (int kb = 0; kb < 8; ++kb)
            af[kb] = *(const half8*)&xa[(wrow * 16 + col) * XS + kb * 32 + quad * 8];

        int slm[4];
        #pragma unroll
        for (int mw = 0; mw < 4; ++mw) slm[mw] = __popc(col & TB.meas[mw]) & 1;

        float sS[4] = {0.f, 0.f, 0.f, 0.f};
        float sq[4][4] = {{0.f}};
        const _Float16* bre = Wt + (long)col * 256;
        const _Float16* bim = Wt + (long)(256 + col) * 256;

        #pragma unroll
        for (int cc = 0; cc < 8; ++cc) {
            const int c = whalf * 8 + cc;
            // split accumulators: 4 independent MFMA chains
            f32x4 cr0 = {0.f,0.f,0.f,0.f}, cr1 = {0.f,0.f,0.f,0.f};
            f32x4 ci0 = {0.f,0.f,0.f,0.f}, ci1 = {0.f,0.f,0.f,0.f};
            const long rowoff = (long)(c * 16) * 256 + quad * 8;
            #pragma unroll
            for (int kb = 0; kb < 4; ++kb) {
                const half8 br = coh_load_h8(bre + rowoff + kb * 32);
                cr0 = __builtin_amdgcn_mfma_f32_16x16x32_f16(af[kb], br, cr0, 0, 0, 0);
                const half8 bi = coh_load_h8(bim + rowoff + kb * 32);
                ci0 = __builtin_amdgcn_mfma_f32_16x16x32_f16(af[kb], bi, ci0, 0, 0, 0);
                const half8 br2 = coh_load_h8(bre + rowoff + (kb + 4) * 32);
                cr1 = __builtin_amdgcn_mfma_f32_16x16x32_f16(af[kb + 4], br2, cr1, 0, 0, 0);
                const half8 bi2 = coh_load_h8(bim + rowoff + (kb + 4) * 32);
                ci1 = __builtin_amdgcn_mfma_f32_16x16x32_f16(af[kb + 4], bi2, ci1, 0, 0, 0);
            }
            float sgn[4];
            #pragma unroll
            for (int mw = 0; mw < 4; ++mw) {
                const int scw = __builtin_popcount((c * 16) & TB.meas[mw]) & 1;  // folds
                sgn[mw] = (slm[mw] ^ scw) ? -1.f : 1.f;
            }
            #pragma unroll
            for (int r = 0; r < 4; ++r) {
                const float re = cr0[r] + cr1[r], im = ci0[r] + ci1[r];
                const float p = re * re + im * im;
                sS[r] += p;
                #pragma unroll
                for (int mw = 0; mw < 4; ++mw) sq[mw][r] = fmaf(sgn[mw], p, sq[mw][r]);
            }
        }

        // all-reduce across the 16-lane col dimension (i-columns)
        #pragma unroll
        for (int r = 0; r < 4; ++r) {
            sS[r] += lanex<1>(sS[r]); sS[r] += lanex<2>(sS[r]);
            sS[r] += lanex<4>(sS[r]); sS[r] += lanex<8>(sS[r]);
            #pragma unroll
            for (int mw = 0; mw < 4; ++mw) {
                sq[mw][r] += lanex<1>(sq[mw][r]); sq[mw][r] += lanex<2>(sq[mw][r]);
                sq[mw][r] += lanex<4>(sq[mw][r]); sq[mw][r] += lanex<8>(sq[mw][r]);
            }
        }

        if (col == 0) {   // combine the two column-halves via LDS atomics
            #pragma unroll
            for (int r = 0; r < 4; ++r) {
                const int mloc = wrow * 16 + quad * 4 + r;
                atomicAdd(&pS[mloc], sS[r]);
                #pragma unroll
                for (int mw = 0; mw < 4; ++mw) atomicAdd(&pQ[mw][mloc], sq[mw][r]);
            }
        }
    }
    __syncthreads();
    if (t < 32) {
        const float inv = 1.0f / pS[t];            // folds AmplitudeEmbedding norm
        float qe[4];
        #pragma unroll
        for (int mw = 0; mw < 4; ++mw) qe[mw] = pQ[mw][t] * inv;
        #pragma unroll
        for (int kk = 0; kk < 4; ++kk) {
            float s = ab[kk] + cfb[t][kk];
            #pragma unroll
            for (int j = 0; j < 4; ++j) s += aW[kk * 4 + j] * qe[j];
            hb[t][kk] = s;
        }
    }
    __syncthreads();
    if (t < 20) {
        const int j = (t - 4) >> 2, kk = (t - 4) & 3;
        float v = 0.f;
        for (int rr = 0; rr < 32; ++rr)
            v += (t < 4) ? hb[rr][t] : hb[rr][j] * hb[rr][kk];
        atomicAdd(acc1 + (b & 31) * 20 + t, v);
    }

    gbar(bar + 256, bar + 848);

    // ======== Phase C: analytic BN1 + relu + layer2 + z2 stats ========
    if (t < 20) {
        float s = 0.f;
        for (int sl = 0; sl < 32; ++sl) s += coh_load_f(&acc1[sl * 20 + t]);
        sA[t] = s;
    }
    __syncthreads();
    if (t < 32) {
        float mu[4], wv[4];
        #pragma unroll
        for (int k = 0; k < 4; ++k) mu[k] = sA[k] * INV_B;
        float m = cb1[t];
        #pragma unroll
        for (int k = 0; k < 4; ++k) { wv[k] = cW1[t * 4 + k]; m += wv[k] * mu[k]; }
        float var = 0.f;
        #pragma unroll
        for (int a2 = 0; a2 < 4; ++a2)
            #pragma unroll
            for (int b2 = 0; b2 < 4; ++b2)
                var += wv[a2] * wv[b2] * (sA[4 + a2 * 4 + b2] * INV_B - mu[a2] * mu[b2]);
        m1s[t] = m;
        is1[t] = 1.0f / sqrtf(var + 1e-5f);
    }
    __syncthreads();

    {   // 256 threads = 32 rows x 8 groups (2 z2-cols each)
        const int row = t & 31, grp = t >> 5;
        const float h0 = hb[row][0], h1 = hb[row][1], h2 = hb[row][2], h3 = hb[row][3];
        float a1[32];
        #pragma unroll
        for (int j = 0; j < 32; ++j) {
            float zz = cb1[j] + cW1[j * 4 + 0] * h0 + cW1[j * 4 + 1] * h1
                              + cW1[j * 4 + 2] * h2 + cW1[j * 4 + 3] * h3;
            a1[j] = fmaxf((zz - m1s[j]) * is1[j] * g1[j] + be1[j], 0.f);
        }
        #pragma unroll
        for (int d = 0; d < 2; ++d) {
            const int kk = grp * 2 + d;
            float s = cb2[kk];
            #pragma unroll
            for (int j = 0; j < 32; ++j) s += cW2[kk * 32 + j] * a1[j];
            z2b[row][kk] = s;
        }
    }
    __syncthreads();
    if (t < 32) {                      // z2 batch moments
        const int colz = t & 15, mode = t >> 4;
        float s = 0.f;
        for (int rr = 0; rr < 32; ++rr) {
            const float v = z2b[rr][colz];
            s += mode ? v * v : v;
        }
        atomicAdd(acc2 + (b & 31) * 32 + mode * 16 + colz, s);
    }

    gbar(bar + 512, bar + 864);

    // ======== Phase D: BN2 + relu + layer3 + layer4 + sigmoid ========
    if (t < 32) {
        float s = 0.f;
        for (int sl = 0; sl < 32; ++sl) s += coh_load_f(&acc2[sl * 32 + t]);
        sB[t] = s;
    }
    __syncthreads();
    if (t < 16) {
        const float m = sB[t] * INV_B;
        const float var = sB[16 + t] * INV_B - m * m;
        m2s[t] = m;
        is2[t] = 1.0f / sqrtf(var + 1e-5f);
    }
    __syncthreads();
    if (t < 32) {
        float a2[16];
        #pragma unroll
        for (int k = 0; k < 16; ++k)
            a2[k] = fmaxf((z2b[t][k] - m2s[k]) * is2[k] * g2[k] + be2[k], 0.f);
        float z3[8];
        #pragma unroll
        for (int j = 0; j < 8; ++j) {
            float s = cb3[j];
            #pragma unroll
            for (int k = 0; k < 16; ++k) s += cW3[j * 16 + k] * a2[k];
            z3[j] = fmaxf(s, 0.f);
        }
        float y = cb4[0];
        #pragma unroll
        for (int j = 0; j < 8; ++j) y += cW4[j] * z3[j];
        out[R0 + t] = 1.0f / (1.0f + expf(-y));
    }
}

// ---------------------------------------------------------------------------
extern "C" void kernel_launch(void* const* d_in, const int* in_sizes, int n_in,
                              void* d_out, int out_size, void* d_ws, size_t ws_size,
                              hipStream_t stream) {
    (void)in_sizes; (void)n_in; (void)out_size; (void)ws_size;
    const float* x   = (const float*)d_in[0];
    const float* qw  = (const float*)d_in[1];
    const float* aW  = (const float*)d_in[2];
    const float* ab  = (const float*)d_in[3];
    const float* fW1 = (const float*)d_in[4];
    const float* fb1 = (const float*)d_in[5];
    const float* fW2 = (const float*)d_in[6];
    const float* fb2 = (const float*)d_in[7];
    const float* cW1 = (const float*)d_in[8];
    const float* cb1 = (const float*)d_in[9];
    const float* g1  = (const float*)d_in[10];
    const float* be1 = (const float*)d_in[11];
    const float* cW2 = (const float*)d_in[12];
    const float* cb2 = (const float*)d_in[13];
    const float* g2  = (const float*)d_in[14];
    const float* be2 = (const float*)d_in[15];
    const float* cW3 = (const float*)d_in[16];
    const float* cb3 = (const float*)d_in[17];
    const float* cW4 = (const float*)d_in[18];
    const float* cb4 = (const float*)d_in[19];

    float* ws    = (float*)d_ws;
    float* acc1  = ws;                         // 640 floats (ws[0..639])
    float* acc2  = ws + 1024;                  // 1024 floats (ws[1024..2047])
    unsigned* bar = (unsigned*)(ws + 2048);    // arr0/arr1/arr2 at +0/+256/+512,
                                               // rel flags at +832/+848/+864 (4KB total)
    _Float16* Wt = (_Float16*)(ws + 215040);   // 512 x 256 f16 = 256 KB
    float* outp  = (float*)d_out;

    hipMemsetAsync(bar, 0, 4096, stream);
    k_fused<<<256, 256, 0, stream>>>(x, qw, fW1, fb1, fW2, fb2, aW, ab,
                                     cW1, cb1, g1, be1, cW2, cb2, g2, be2,
                                     cW3, cb3, cW4, cb4, Wt, acc1, acc2, bar, outp);
}

// Round 6
// 132.683 us; speedup vs baseline: 1.3171x; 1.3171x over previous
//
#include <hip/hip_runtime.h>
#include <math.h>

#define INV_B (1.0f / 8192.0f)

typedef float  v2f  __attribute__((ext_vector_type(2)));
typedef _Float16 half8 __attribute__((ext_vector_type(8)));
typedef float  f32x4 __attribute__((ext_vector_type(4)));
typedef unsigned u32x4 __attribute__((ext_vector_type(4)));

// ---------------------------------------------------------------------------
// Compile-time GF(2) tracking of the CNOT network (R3-verified, absmax 0.0).
// Index i (8 bits): wire w <-> bit (7-w).  Storage: i = 4*lane + reg.
// ---------------------------------------------------------------------------
struct QTables {
    int xm[6][8];   // xor (partner) mask per (layer, wire)
    int rm[6][8];   // row parity mask per (layer, wire)
    int meas[4];    // measurement parity masks on storage index, wires 0..3
};
constexpr QTables make_tables() {
    QTables T{};
    int Mrow[8] = {}, Ncol[8] = {};
    for (int b = 0; b < 8; ++b) { Mrow[b] = 1 << b; Ncol[b] = 1 << b; }
    constexpr int bc[11] = {7,6,5,4,3,2,1,0,7,5,3};
    constexpr int bt[11] = {6,5,4,3,2,1,0,7,5,3,1};
    for (int l = 0; l < 6; ++l) {
        for (int w = 0; w < 8; ++w) { T.xm[l][w] = Ncol[7 - w]; T.rm[l][w] = Mrow[7 - w]; }
        for (int k = 0; k < 11; ++k) { Mrow[bt[k]] ^= Mrow[bc[k]]; Ncol[bc[k]] ^= Ncol[bt[k]]; }
    }
    for (int w = 0; w < 4; ++w) T.meas[w] = Mrow[7 - w];
    return T;
}
constexpr QTables TB = make_tables();

// xor-shuffle along lane mask ML: 1..3 DPP quad_perm (VALU pipe),
// 4..31 ds_swizzle (LDS pipe, immediate offset), >=32 shfl (bpermute).
template<int ML>
static __device__ __forceinline__ float lanex(float v) {
    if constexpr (ML == 0) { return v; }
    else if constexpr (ML == 1) { return __int_as_float(__builtin_amdgcn_update_dpp(0, __float_as_int(v), 0xB1, 0xF, 0xF, true)); }
    else if constexpr (ML == 2) { return __int_as_float(__builtin_amdgcn_update_dpp(0, __float_as_int(v), 0x4E, 0xF, 0xF, true)); }
    else if constexpr (ML == 3) { return __int_as_float(__builtin_amdgcn_update_dpp(0, __float_as_int(v), 0x1B, 0xF, 0xF, true)); }
    else if constexpr (ML < 32) { return __int_as_float(__builtin_amdgcn_ds_swizzle(__float_as_int(v), 0x1F | (ML << 10))); }
    else { return __shfl_xor(v, ML, 64); }
}

static __device__ __forceinline__ float tanh_fast(float v) {
    const float c = fminf(fmaxf(v, -10.f), 10.f);
    const float e = __expf(2.f * c);
    return (e - 1.f) / (e + 1.f);
}

// Coherent (agent-scope) helpers. All cross-block traffic is agent-coherent
// => NO L2 fences (wbl2/inv) anywhere. Correctness of this scheme proven on
// HW in R5 (passed, absmax unchanged).
static __device__ __forceinline__ void coh_store_h(_Float16* p, _Float16 v) {
    __hip_atomic_store((short*)p, __builtin_bit_cast(short, v),
                       __ATOMIC_RELAXED, __HIP_MEMORY_SCOPE_AGENT);
}
static __device__ __forceinline__ void coh_store_f(float* p, float v) {
    __hip_atomic_store(p, v, __ATOMIC_RELAXED, __HIP_MEMORY_SCOPE_AGENT);
}
static __device__ __forceinline__ float coh_load_f(const float* p) {
    return __hip_atomic_load(p, __ATOMIC_RELAXED, __HIP_MEMORY_SCOPE_AGENT);
}

// WIDE agent-coherent loads for the Phase-B hot loop: 4x global_load_dwordx4
// sc1 (same agent scope R5's 4B atomic loads lowered to -- L3-served, proven
// correct) with ONE vmcnt wait per group. Early-clobber outputs: a result
// landing early must not alias a later load's address pair.
static __device__ __forceinline__ void coh_load4_h8(
        const _Float16* p0, const _Float16* p1,
        const _Float16* p2, const _Float16* p3,
        half8& r0, half8& r1, half8& r2, half8& r3) {
    u32x4 a, b, c, d;
    asm volatile(
        "global_load_dwordx4 %0, %4, off sc1\n\t"
        "global_load_dwordx4 %1, %5, off sc1\n\t"
        "global_load_dwordx4 %2, %6, off sc1\n\t"
        "global_load_dwordx4 %3, %7, off sc1\n\t"
        "s_waitcnt vmcnt(0)"
        : "=&v"(a), "=&v"(b), "=&v"(c), "=&v"(d)
        : "v"(p0), "v"(p1), "v"(p2), "v"(p3)
        : "memory");
    r0 = __builtin_bit_cast(half8, a);
    r1 = __builtin_bit_cast(half8, b);
    r2 = __builtin_bit_cast(half8, c);
    r3 = __builtin_bit_cast(half8, d);
}

// Fused SU(2) gate, packed complex (R3/R5-verified math).
template<int XM, int RM>
static __device__ __forceinline__ void gate(v2f (&z)[4], const int lane,
                                            const float u00r, const float u00i,
                                            const float u01r, const float u01i) {
    constexpr int ML = XM >> 2, MR = XM & 3;
    constexpr int RL = RM >> 2, RR = RM & 3;
    const int pl = __popc(lane & RL) & 1;
    const float csi0 = pl ? -u00i : u00i;
    const float cpr0 = pl ? -u01r : u01r;
    const float csi1 = -csi0, cpr1 = -cpr0;
    v2f p[4];
    #pragma unroll
    for (int r = 0; r < 4; ++r) {
        p[r].x = lanex<ML>(z[r ^ MR].x);
        p[r].y = lanex<ML>(z[r ^ MR].y);
    }
    #pragma unroll
    for (int r = 0; r < 4; ++r) {
        const int pb = __builtin_popcount(r & RR) & 1;
        const float csi = pb ? csi1 : csi0;
        const float cpr = pb ? cpr1 : cpr0;
        const v2f zs = { -z[r].y, z[r].x };
        const v2f ps = { -p[r].y, p[r].x };
        z[r] = ((u00r * z[r] + csi * zs) + cpr * p[r]) + u01i * ps;
    }
}

// ---------------------------------------------------------------------------
// Fence-FREE grid barrier (256 blocks = 1/CU, co-residency proven R2-R5).
// All cross-block data is agent-coherent, so no L2 writeback/invalidate is
// needed. __syncthreads before arrival drains vmcnt, so a block's coherent
// writes reach the coherence point before its arrival store.
// ---------------------------------------------------------------------------
static __device__ __forceinline__ void gbar(unsigned* arr, unsigned* rel) {
    __syncthreads();
    if (blockIdx.x == 0) {
        if (threadIdx.x != 0) {        // poll arrival slot of block threadIdx.x
            while (!__hip_atomic_load(&arr[threadIdx.x], __ATOMIC_RELAXED,
                                      __HIP_MEMORY_SCOPE_AGENT))
                __builtin_amdgcn_s_sleep(4);
        }
        __syncthreads();               // all arrivals seen
        if (threadIdx.x == 0)
            __hip_atomic_store(rel, 1u, __ATOMIC_RELAXED, __HIP_MEMORY_SCOPE_AGENT);
        __syncthreads();
    } else {
        if (threadIdx.x == 0) {
            __hip_atomic_store(&arr[blockIdx.x], 1u, __ATOMIC_RELAXED,
                               __HIP_MEMORY_SCOPE_AGENT);
            while (!__hip_atomic_load(rel, __ATOMIC_RELAXED, __HIP_MEMORY_SCOPE_AGENT))
                __builtin_amdgcn_s_sleep(4);
        }
        __syncthreads();
    }
}

#define XS 264   // padded LDS stride in halves (528B, 16B-divisible)

// ---------------------------------------------------------------------------
// Single fused kernel, 256 blocks x 256 threads (4 waves), 3 grid barriers.
// Phase A: stage x tile (32 rows) once; wave0 builds basis state k=blockIdx.x
//          of the circuit operator W; waves1-2 cf MLP (MFMA); wave3 zeroes.
// Phase B: ALL 4 waves run the quantum gemm: wave&1 = row tile, wave>>1 =
//          column half (c 0..7 / 8..15); partials combined via LDS atomics.
//          Wt reads via wide sc1 loads (L3-served, fence-free coherence).
// Phase C: analytic BN1 + relu + layer2 -> z2 (LDS) + z2 stats atomics.
// Phase D: BN2 + relu + layer3 + layer4 + sigmoid -> out.
// All math verbatim from the R0/R3/R5-verified version.
// ---------------------------------------------------------------------------
__global__ __launch_bounds__(256) void k_fused(
        const float* __restrict__ x, const float* __restrict__ qw,
        const float* __restrict__ fW1, const float* __restrict__ fb1,
        const float* __restrict__ fW2, const float* __restrict__ fb2,
        const float* __restrict__ aW, const float* __restrict__ ab,
        const float* __restrict__ cW1, const float* __restrict__ cb1,
        const float* __restrict__ g1, const float* __restrict__ be1,
        const float* __restrict__ cW2, const float* __restrict__ cb2,
        const float* __restrict__ g2, const float* __restrict__ be2,
        const float* __restrict__ cW3, const float* __restrict__ cb3,
        const float* __restrict__ cW4, const float* __restrict__ cb4,
        _Float16* __restrict__ Wt, float* __restrict__ acc1,
        float* __restrict__ acc2, unsigned* __restrict__ bar,
        float* __restrict__ out)
{
    const int t = threadIdx.x, b = blockIdx.x;
    const int lane = t & 63, w = t >> 6;
    const int R0 = b * 32;

    __shared__ _Float16 xa[32 * XS];     // x tile, f16 (32 rows x 256)
    __shared__ float4 Us[48];            // per-gate SU(2) params
    __shared__ float cfb[32][4];         // cf (feature MLP output)
    __shared__ float hb[32][4];          // h
    __shared__ float z2b[32][16];        // z2
    __shared__ float pS[32];             // phase-B partial |amp|^2 sums
    __shared__ float pQ[4][32];          // phase-B partial signed sums
    __shared__ float sA[20];
    __shared__ float m1s[32], is1[32];
    __shared__ float sB[32];
    __shared__ float m2s[16], is2[16];

    // ======== Phase A ========
    // stage x rows R0..R0+31 as f16 (the ONLY x read for this block)
    #pragma unroll
    for (int i = 0; i < 8; ++i) {
        const int idx = i * 256 + t;
        const int row = idx >> 6, c4 = idx & 63;
        const float4 xv = ((const float4*)(x + (long)(R0 + row) * 256))[c4];
        _Float16* d = &xa[row * XS + c4 * 4];
        d[0] = (_Float16)xv.x; d[1] = (_Float16)xv.y;
        d[2] = (_Float16)xv.z; d[3] = (_Float16)xv.w;
    }
    if (t < 48) {
        const int l = t >> 3, q = t & 7;
        const float* a = qw + l * 24 + q * 3;
        const float h1 = 0.5f * a[0], h2 = 0.5f * a[1], h3 = 0.5f * a[2];
        const float c1 = cosf(h1), s1 = sinf(h1);
        const float c2 = cosf(h2), s2 = sinf(h2);
        const float c3 = cosf(h3), s3 = sinf(h3);
        const float m00r =  c1 * c2, m00i =  s1 * s2;   // (Ry*Rx) row 0
        const float m01r = -c1 * s2, m01i = -s1 * c2;
        float4 u;
        u.x = m00r * c3 + m00i * s3;  u.y = m00i * c3 - m00r * s3;  // u00 e^{-i h3}
        u.z = m01r * c3 + m01i * s3;  u.w = m01i * c3 - m01r * s3;  // u01 e^{-i h3}
        Us[t] = u;
    }
    if (t >= 192 && t < 224) {          // zero phase-B LDS partials
        const int r = t - 192;
        pS[r] = 0.f;
        pQ[0][r] = 0.f; pQ[1][r] = 0.f; pQ[2][r] = 0.f; pQ[3][r] = 0.f;
    }
    if (b < 32 && w == 3) {             // zero accumulator slots (coherent: ws poisoned)
        const int l = t - 192;
        if (l < 20) coh_store_f(&acc1[b * 20 + l], 0.f);
        if (l < 32) coh_store_f(&acc2[b * 32 + l], 0.f);
    }
    __syncthreads();

    if (w == 0) {
        // ---- quantum operator build: basis state k = blockIdx.x (fp32 exact)
        const int k = b;
        v2f z[4];
        #pragma unroll
        for (int r = 0; r < 4; ++r) {
            z[r].x = (4 * lane + r == k) ? 1.f : 0.f;
            z[r].y = 0.f;
        }
#define GATE(L, W) { const float4 u = Us[(L) * 8 + (W)]; \
                     gate<TB.xm[L][W], TB.rm[L][W]>(z, lane, u.x, u.y, u.z, u.w); }
#define LAYER(L) GATE(L,0) GATE(L,1) GATE(L,2) GATE(L,3) GATE(L,4) GATE(L,5) GATE(L,6) GATE(L,7)
        LAYER(0) LAYER(1) LAYER(2) LAYER(3) LAYER(4) LAYER(5)
#undef LAYER
#undef GATE
        #pragma unroll
        for (int r = 0; r < 4; ++r) {
            const int i = 4 * lane + r;            // storage index
            coh_store_h(&Wt[(long)i * 256 + k],         (_Float16)z[r].x);
            coh_store_h(&Wt[(long)(256 + i) * 256 + k], (_Float16)z[r].y);
        }
    } else if (w <= 2) {
        // ---- cf MLP for m-tile (w-1): rows mt*16..+15 (R5-verified math)
        const int g = lane >> 4, col = lane & 15;
        const int mt = w - 1;
        half8 bf[8];
        #pragma unroll
        for (int kb = 0; kb < 8; ++kb)
            bf[kb] = *(const half8*)&xa[(mt * 16 + col) * XS + kb * 32 + g * 8];
        float accc[4] = {0.f, 0.f, 0.f, 0.f};
        #pragma unroll
        for (int jc = 0; jc < 4; ++jc) {
            f32x4 cv = {0.f, 0.f, 0.f, 0.f};
            #pragma unroll
            for (int kb = 0; kb < 8; ++kb) {
                const float* ap = fW1 + (long)(jc * 16 + col) * 256 + kb * 32 + g * 8;
                const float4 a0 = *(const float4*)ap;
                const float4 a1v = *(const float4*)(ap + 4);
                half8 af;
                af[0] = (_Float16)a0.x;  af[1] = (_Float16)a0.y;
                af[2] = (_Float16)a0.z;  af[3] = (_Float16)a0.w;
                af[4] = (_Float16)a1v.x; af[5] = (_Float16)a1v.y;
                af[6] = (_Float16)a1v.z; af[7] = (_Float16)a1v.w;
                cv = __builtin_amdgcn_mfma_f32_16x16x32_f16(af, bf[kb], cv, 0, 0, 0);
            }
            #pragma unroll
            for (int r = 0; r < 4; ++r) {
                const int j = jc * 16 + g * 4 + r;
                const float z = fmaxf(cv[r] + fb1[j], 0.f);
                #pragma unroll
                for (int c = 0; c < 4; ++c) accc[c] += z * fW2[c * 64 + j];
            }
        }
        #pragma unroll
        for (int c = 0; c < 4; ++c) {
            accc[c] += __shfl_xor(accc[c], 16, 64);
            accc[c] += __shfl_xor(accc[c], 32, 64);
        }
        if (g == 0) {
            cfb[mt * 16 + col][0] = tanh_fast(accc[0] + fb2[0]);
            cfb[mt * 16 + col][1] = tanh_fast(accc[1] + fb2[1]);
            cfb[mt * 16 + col][2] = tanh_fast(accc[2] + fb2[2]);
            cfb[mt * 16 + col][3] = tanh_fast(accc[3] + fb2[3]);
        }
    }

    gbar(bar, bar + 832);

    // ======== Phase B: quantum gemm, ALL 4 waves (R5-verified frag maps) ====
    {
        const int col = lane & 15, quad = lane >> 4;
        const int wrow = w & 1;          // row tile (rows wrow*16..+15)
        const int whalf = w >> 1;        // column half (c = whalf*8 + cc)
        half8 af[8];
        #pragma unroll
        for (int kb = 0; kb < 8; ++kb)
            af[kb] = *(const half8*)&xa[(wrow * 16 + col) * XS + kb * 32 + quad * 8];

        int slm[4];
        #pragma unroll
        for (int mw = 0; mw < 4; ++mw) slm[mw] = __popc(col & TB.meas[mw]) & 1;

        float sS[4] = {0.f, 0.f, 0.f, 0.f};
        float sq[4][4] = {{0.f}};
        const _Float16* bre = Wt + (long)col * 256;
        const _Float16* bim = Wt + (long)(256 + col) * 256;

        #pragma unroll
        for (int cc = 0; cc < 8; ++cc) {
            const int c = whalf * 8 + cc;
            // split accumulators: 4 independent MFMA chains
            f32x4 cr0 = {0.f,0.f,0.f,0.f}, cr1 = {0.f,0.f,0.f,0.f};
            f32x4 ci0 = {0.f,0.f,0.f,0.f}, ci1 = {0.f,0.f,0.f,0.f};
            const long rowoff = (long)(c * 16) * 256 + quad * 8;
            #pragma unroll
            for (int kb = 0; kb < 4; ++kb) {
                half8 br, bi, br2, bi2;
                coh_load4_h8(bre + rowoff + kb * 32,       bim + rowoff + kb * 32,
                             bre + rowoff + (kb + 4) * 32, bim + rowoff + (kb + 4) * 32,
                             br, bi, br2, bi2);
                cr0 = __builtin_amdgcn_mfma_f32_16x16x32_f16(af[kb], br, cr0, 0, 0, 0);
                ci0 = __builtin_amdgcn_mfma_f32_16x16x32_f16(af[kb], bi, ci0, 0, 0, 0);
                cr1 = __builtin_amdgcn_mfma_f32_16x16x32_f16(af[kb + 4], br2, cr1, 0, 0, 0);
                ci1 = __builtin_amdgcn_mfma_f32_16x16x32_f16(af[kb + 4], bi2, ci1, 0, 0, 0);
            }
            float sgn[4];
            #pragma unroll
            for (int mw = 0; mw < 4; ++mw) {
                const int scw = __builtin_popcount((c * 16) & TB.meas[mw]) & 1;  // folds
                sgn[mw] = (slm[mw] ^ scw) ? -1.f : 1.f;
            }
            #pragma unroll
            for (int r = 0; r < 4; ++r) {
                const float re = cr0[r] + cr1[r], im = ci0[r] + ci1[r];
                const float p = re * re + im * im;
                sS[r] += p;
                #pragma unroll
                for (int mw = 0; mw < 4; ++mw) sq[mw][r] = fmaf(sgn[mw], p, sq[mw][r]);
            }
        }

        // all-reduce across the 16-lane col dimension (i-columns)
        #pragma unroll
        for (int r = 0; r < 4; ++r) {
            sS[r] += lanex<1>(sS[r]); sS[r] += lanex<2>(sS[r]);
            sS[r] += lanex<4>(sS[r]); sS[r] += lanex<8>(sS[r]);
            #pragma unroll
            for (int mw = 0; mw < 4; ++mw) {
                sq[mw][r] += lanex<1>(sq[mw][r]); sq[mw][r] += lanex<2>(sq[mw][r]);
                sq[mw][r] += lanex<4>(sq[mw][r]); sq[mw][r] += lanex<8>(sq[mw][r]);
            }
        }

        if (col == 0) {   // combine the two column-halves via LDS atomics
            #pragma unroll
            for (int r = 0; r < 4; ++r) {
                const int mloc = wrow * 16 + quad * 4 + r;
                atomicAdd(&pS[mloc], sS[r]);
                #pragma unroll
                for (int mw = 0; mw < 4; ++mw) atomicAdd(&pQ[mw][mloc], sq[mw][r]);
            }
        }
    }
    __syncthreads();
    if (t < 32) {
        const float inv = 1.0f / pS[t];            // folds AmplitudeEmbedding norm
        float qe[4];
        #pragma unroll
        for (int mw = 0; mw < 4; ++mw) qe[mw] = pQ[mw][t] * inv;
        #pragma unroll
        for (int kk = 0; kk < 4; ++kk) {
            float s = ab[kk] + cfb[t][kk];
            #pragma unroll
            for (int j = 0; j < 4; ++j) s += aW[kk * 4 + j] * qe[j];
            hb[t][kk] = s;
        }
    }
    __syncthreads();
    if (t < 20) {
        const int j = (t - 4) >> 2, kk = (t - 4) & 3;
        float v = 0.f;
        for (int rr = 0; rr < 32; ++rr)
            v += (t < 4) ? hb[rr][t] : hb[rr][j] * hb[rr][kk];
        atomicAdd(acc1 + (b & 31) * 20 + t, v);
    }

    gbar(bar + 256, bar + 848);

    // ======== Phase C: analytic BN1 + relu + layer2 + z2 stats ========
    if (t < 20) {
        float s = 0.f;
        for (int sl = 0; sl < 32; ++sl) s += coh_load_f(&acc1[sl * 20 + t]);
        sA[t] = s;
    }
    __syncthreads();
    if (t < 32) {
        float mu[4], wv[4];
        #pragma unroll
        for (int k = 0; k < 4; ++k) mu[k] = sA[k] * INV_B;
        float m = cb1[t];
        #pragma unroll
        for (int k = 0; k < 4; ++k) { wv[k] = cW1[t * 4 + k]; m += wv[k] * mu[k]; }
        float var = 0.f;
        #pragma unroll
        for (int a2 = 0; a2 < 4; ++a2)
            #pragma unroll
            for (int b2 = 0; b2 < 4; ++b2)
                var += wv[a2] * wv[b2] * (sA[4 + a2 * 4 + b2] * INV_B - mu[a2] * mu[b2]);
        m1s[t] = m;
        is1[t] = 1.0f / sqrtf(var + 1e-5f);
    }
    __syncthreads();

    {   // 256 threads = 32 rows x 8 groups (2 z2-cols each)
        const int row = t & 31, grp = t >> 5;
        const float h0 = hb[row][0], h1 = hb[row][1], h2 = hb[row][2], h3 = hb[row][3];
        float a1[32];
        #pragma unroll
        for (int j = 0; j < 32; ++j) {
            float zz = cb1[j] + cW1[j * 4 + 0] * h0 + cW1[j * 4 + 1] * h1
                              + cW1[j * 4 + 2] * h2 + cW1[j * 4 + 3] * h3;
            a1[j] = fmaxf((zz - m1s[j]) * is1[j] * g1[j] + be1[j], 0.f);
        }
        #pragma unroll
        for (int d = 0; d < 2; ++d) {
            const int kk = grp * 2 + d;
            float s = cb2[kk];
            #pragma unroll
            for (int j = 0; j < 32; ++j) s += cW2[kk * 32 + j] * a1[j];
            z2b[row][kk] = s;
        }
    }
    __syncthreads();
    if (t < 32) {                      // z2 batch moments
        const int colz = t & 15, mode = t >> 4;
        float s = 0.f;
        for (int rr = 0; rr < 32; ++rr) {
            const float v = z2b[rr][colz];
            s += mode ? v * v : v;
        }
        atomicAdd(acc2 + (b & 31) * 32 + mode * 16 + colz, s);
    }

    gbar(bar + 512, bar + 864);

    // ======== Phase D: BN2 + relu + layer3 + layer4 + sigmoid ========
    if (t < 32) {
        float s = 0.f;
        for (int sl = 0; sl < 32; ++sl) s += coh_load_f(&acc2[sl * 32 + t]);
        sB[t] = s;
    }
    __syncthreads();
    if (t < 16) {
        const float m = sB[t] * INV_B;
        const float var = sB[16 + t] * INV_B - m * m;
        m2s[t] = m;
        is2[t] = 1.0f / sqrtf(var + 1e-5f);
    }
    __syncthreads();
    if (t < 32) {
        float a2[16];
        #pragma unroll
        for (int k = 0; k < 16; ++k)
            a2[k] = fmaxf((z2b[t][k] - m2s[k]) * is2[k] * g2[k] + be2[k], 0.f);
        float z3[8];
        #pragma unroll
        for (int j = 0; j < 8; ++j) {
            float s = cb3[j];
            #pragma unroll
            for (int k = 0; k < 16; ++k) s += cW3[j * 16 + k] * a2[k];
            z3[j] = fmaxf(s, 0.f);
        }
        float y = cb4[0];
        #pragma unroll
        for (int j = 0; j < 8; ++j) y += cW4[j] * z3[j];
        out[R0 + t] = 1.0f / (1.0f + expf(-y));
    }
}

// ---------------------------------------------------------------------------
extern "C" void kernel_launch(void* const* d_in, const int* in_sizes, int n_in,
                              void* d_out, int out_size, void* d_ws, size_t ws_size,
                              hipStream_t stream) {
    (void)in_sizes; (void)n_in; (void)out_size; (void)ws_size;
    const float* x   = (const float*)d_in[0];
    const float* qw  = (const float*)d_in[1];
    const float* aW  = (const float*)d_in[2];
    const float* ab  = (const float*)d_in[3];
    const float* fW1 = (const float*)d_in[4];
    const float* fb1 = (const float*)d_in[5];
    const float* fW2 = (const float*)d_in[6];
    const float* fb2 = (const float*)d_in[7];
    const float* cW1 = (const float*)d_in[8];
    const float* cb1 = (const float*)d_in[9];
    const float* g1  = (const float*)d_in[10];
    const float* be1 = (const float*)d_in[11];
    const float* cW2 = (const float*)d_in[12];
    const float* cb2 = (const float*)d_in[13];
    const float* g2  = (const float*)d_in[14];
    const float* be2 = (const float*)d_in[15];
    const float* cW3 = (const float*)d_in[16];
    const float* cb3 = (const float*)d_in[17];
    const float* cW4 = (const float*)d_in[18];
    const float* cb4 = (const float*)d_in[19];

    float* ws    = (float*)d_ws;
    float* acc1  = ws;                         // 640 floats (ws[0..639])
    float* acc2  = ws + 1024;                  // 1024 floats (ws[1024..2047])
    unsigned* bar = (unsigned*)(ws + 2048);    // arr0/arr1/arr2 at +0/+256/+512,
                                               // rel flags at +832/+848/+864 (4KB total)
    _Float16* Wt = (_Float16*)(ws + 215040);   // 512 x 256 f16 = 256 KB
    float* outp  = (float*)d_out;

    hipMemsetAsync(bar, 0, 4096, stream);
    k_fused<<<256, 256, 0, stream>>>(x, qw, fW1, fb1, fW2, fb2, aW, ab,
                                     cW1, cb1, g1, be1, cW2, cb2, g2, be2,
                                     cW3, cb3, cW4, cb4, Wt, acc1, acc2, bar, outp);
}

// Round 7
// 132.471 us; speedup vs baseline: 1.3192x; 1.0016x over previous
//
#include <hip/hip_runtime.h>
#include <math.h>

#define INV_B (1.0f / 8192.0f)

typedef float  v2f  __attribute__((ext_vector_type(2)));
typedef _Float16 half8 __attribute__((ext_vector_type(8)));
typedef float  f32x4 __attribute__((ext_vector_type(4)));
typedef unsigned u32x4 __attribute__((ext_vector_type(4)));

// ---------------------------------------------------------------------------
// Compile-time GF(2) tracking of the CNOT network (R3-verified, absmax 0.0).
// Index i (8 bits): wire w <-> bit (7-w).  Storage: i = 4*lane + reg.
// ---------------------------------------------------------------------------
struct QTables {
    int xm[6][8];   // xor (partner) mask per (layer, wire)
    int rm[6][8];   // row parity mask per (layer, wire)
    int meas[4];    // measurement parity masks on storage index, wires 0..3
};
constexpr QTables make_tables() {
    QTables T{};
    int Mrow[8] = {}, Ncol[8] = {};
    for (int b = 0; b < 8; ++b) { Mrow[b] = 1 << b; Ncol[b] = 1 << b; }
    constexpr int bc[11] = {7,6,5,4,3,2,1,0,7,5,3};
    constexpr int bt[11] = {6,5,4,3,2,1,0,7,5,3,1};
    for (int l = 0; l < 6; ++l) {
        for (int w = 0; w < 8; ++w) { T.xm[l][w] = Ncol[7 - w]; T.rm[l][w] = Mrow[7 - w]; }
        for (int k = 0; k < 11; ++k) { Mrow[bt[k]] ^= Mrow[bc[k]]; Ncol[bc[k]] ^= Ncol[bt[k]]; }
    }
    for (int w = 0; w < 4; ++w) T.meas[w] = Mrow[7 - w];
    return T;
}
constexpr QTables TB = make_tables();

// xor-shuffle along lane mask ML: 1..3 DPP quad_perm (VALU pipe),
// 4..31 ds_swizzle (LDS pipe, immediate offset), >=32 shfl (bpermute).
template<int ML>
static __device__ __forceinline__ float lanex(float v) {
    if constexpr (ML == 0) { return v; }
    else if constexpr (ML == 1) { return __int_as_float(__builtin_amdgcn_update_dpp(0, __float_as_int(v), 0xB1, 0xF, 0xF, true)); }
    else if constexpr (ML == 2) { return __int_as_float(__builtin_amdgcn_update_dpp(0, __float_as_int(v), 0x4E, 0xF, 0xF, true)); }
    else if constexpr (ML == 3) { return __int_as_float(__builtin_amdgcn_update_dpp(0, __float_as_int(v), 0x1B, 0xF, 0xF, true)); }
    else if constexpr (ML < 32) { return __int_as_float(__builtin_amdgcn_ds_swizzle(__float_as_int(v), 0x1F | (ML << 10))); }
    else { return __shfl_xor(v, ML, 64); }
}

static __device__ __forceinline__ float tanh_fast(float v) {
    const float c = fminf(fmaxf(v, -10.f), 10.f);
    const float e = __expf(2.f * c);
    return (e - 1.f) / (e + 1.f);
}

// Coherent (agent-scope) helpers. All cross-block traffic is agent-coherent
// => NO L2 fences (wbl2/inv) anywhere. Proven on HW in R5/R6.
static __device__ __forceinline__ void coh_store_h(_Float16* p, _Float16 v) {
    __hip_atomic_store((short*)p, __builtin_bit_cast(short, v),
                       __ATOMIC_RELAXED, __HIP_MEMORY_SCOPE_AGENT);
}
static __device__ __forceinline__ void coh_store_f(float* p, float v) {
    __hip_atomic_store(p, v, __ATOMIC_RELAXED, __HIP_MEMORY_SCOPE_AGENT);
}
static __device__ __forceinline__ float coh_load_f(const float* p) {
    return __hip_atomic_load(p, __ATOMIC_RELAXED, __HIP_MEMORY_SCOPE_AGENT);
}

// Fused SU(2) gate, packed complex (R3/R5-verified math).
template<int XM, int RM>
static __device__ __forceinline__ void gate(v2f (&z)[4], const int lane,
                                            const float u00r, const float u00i,
                                            const float u01r, const float u01i) {
    constexpr int ML = XM >> 2, MR = XM & 3;
    constexpr int RL = RM >> 2, RR = RM & 3;
    const int pl = __popc(lane & RL) & 1;
    const float csi0 = pl ? -u00i : u00i;
    const float cpr0 = pl ? -u01r : u01r;
    const float csi1 = -csi0, cpr1 = -cpr0;
    v2f p[4];
    #pragma unroll
    for (int r = 0; r < 4; ++r) {
        p[r].x = lanex<ML>(z[r ^ MR].x);
        p[r].y = lanex<ML>(z[r ^ MR].y);
    }
    #pragma unroll
    for (int r = 0; r < 4; ++r) {
        const int pb = __builtin_popcount(r & RR) & 1;
        const float csi = pb ? csi1 : csi0;
        const float cpr = pb ? cpr1 : cpr0;
        const v2f zs = { -z[r].y, z[r].x };
        const v2f ps = { -p[r].y, p[r].x };
        z[r] = ((u00r * z[r] + csi * zs) + cpr * p[r]) + u01i * ps;
    }
}

// ---------------------------------------------------------------------------
// Fence-FREE grid barrier, 16-line release fan-out (R6 was a single rel word
// polled by 255 CUs -> one L3 line serialized the release). Arrival: relaxed
// agent store to own slot (16 lines of 16 words). Block 0: 255 threads poll
// arrival slots, then threads 0..15 set 16 replicated rel words in DISTINCT
// lines; block b polls line (b & 15) only.
// ---------------------------------------------------------------------------
static __device__ __forceinline__ void gbar(unsigned* arr, unsigned* rel) {
    __syncthreads();
    if (blockIdx.x == 0) {
        if (threadIdx.x != 0) {
            while (!__hip_atomic_load(&arr[threadIdx.x], __ATOMIC_RELAXED,
                                      __HIP_MEMORY_SCOPE_AGENT))
                __builtin_amdgcn_s_sleep(2);
        }
        __syncthreads();               // all arrivals seen
        if (threadIdx.x < 16)
            __hip_atomic_store(&rel[threadIdx.x * 16], 1u, __ATOMIC_RELAXED,
                               __HIP_MEMORY_SCOPE_AGENT);
        __syncthreads();
    } else {
        if (threadIdx.x == 0) {
            __hip_atomic_store(&arr[blockIdx.x], 1u, __ATOMIC_RELAXED,
                               __HIP_MEMORY_SCOPE_AGENT);
            unsigned* myrel = rel + (blockIdx.x & 15) * 16;
            while (!__hip_atomic_load(myrel, __ATOMIC_RELAXED, __HIP_MEMORY_SCOPE_AGENT))
                __builtin_amdgcn_s_sleep(2);
        }
        __syncthreads();
    }
}

#define XS 264   // padded LDS stride in halves (528B, 16B-divisible)

// ---- Phase-B pipelined load/compute machinery (T3/T4 counted-vmcnt) -------
// ISS: one asm batch of 16 dwordx4 sc1 loads (8 re + 8 im, imm offsets
// kb*64B). WAIT16 leaves the most-recent 16 loads (the just-issued other
// buffer) in flight; any compiler-interleaved vmem only makes the wait
// stricter (vmcnt waits oldest-first), so the consumed buffer is always
// complete. sched_barrier(0) after each wait stops hipcc hoisting MFMAs
// above the inline-asm wait (rule #18).
#define ISS(B, pr, pi) asm volatile( \
    "global_load_dwordx4 %0, %16, off sc1\n\t" \
    "global_load_dwordx4 %1, %16, off offset:64 sc1\n\t" \
    "global_load_dwordx4 %2, %16, off offset:128 sc1\n\t" \
    "global_load_dwordx4 %3, %16, off offset:192 sc1\n\t" \
    "global_load_dwordx4 %4, %16, off offset:256 sc1\n\t" \
    "global_load_dwordx4 %5, %16, off offset:320 sc1\n\t" \
    "global_load_dwordx4 %6, %16, off offset:384 sc1\n\t" \
    "global_load_dwordx4 %7, %16, off offset:448 sc1\n\t" \
    "global_load_dwordx4 %8, %17, off sc1\n\t" \
    "global_load_dwordx4 %9, %17, off offset:64 sc1\n\t" \
    "global_load_dwordx4 %10, %17, off offset:128 sc1\n\t" \
    "global_load_dwordx4 %11, %17, off offset:192 sc1\n\t" \
    "global_load_dwordx4 %12, %17, off offset:256 sc1\n\t" \
    "global_load_dwordx4 %13, %17, off offset:320 sc1\n\t" \
    "global_load_dwordx4 %14, %17, off offset:384 sc1\n\t" \
    "global_load_dwordx4 %15, %17, off offset:448 sc1" \
    : "=&v"(B##0), "=&v"(B##1), "=&v"(B##2), "=&v"(B##3), \
      "=&v"(B##4), "=&v"(B##5), "=&v"(B##6), "=&v"(B##7), \
      "=&v"(B##8), "=&v"(B##9), "=&v"(B##10), "=&v"(B##11), \
      "=&v"(B##12), "=&v"(B##13), "=&v"(B##14), "=&v"(B##15) \
    : "v"(pr), "v"(pi) : "memory")

#define WAIT16 do { asm volatile("s_waitcnt vmcnt(16)" ::: "memory"); \
                    __builtin_amdgcn_sched_barrier(0); } while (0)
#define WAIT0  do { asm volatile("s_waitcnt vmcnt(0)" ::: "memory"); \
                    __builtin_amdgcn_sched_barrier(0); } while (0)

#define MF(A, Bv, C) __builtin_amdgcn_mfma_f32_16x16x32_f16((A), \
                        __builtin_bit_cast(half8, (Bv)), (C), 0, 0, 0)

// Per-accumulator MFMA order identical to R6 (cr0: kb0-3 re, ci0: kb0-3 im,
// cr1/ci1: kb4-7) => bit-identical sums.
#define CMP(B, CC) { \
    f32x4 cr0 = {0.f,0.f,0.f,0.f}, ci0 = {0.f,0.f,0.f,0.f}; \
    f32x4 cr1 = {0.f,0.f,0.f,0.f}, ci1 = {0.f,0.f,0.f,0.f}; \
    cr0 = MF(af[0], B##0, cr0);  ci0 = MF(af[0], B##8,  ci0); \
    cr1 = MF(af[4], B##4, cr1);  ci1 = MF(af[4], B##12, ci1); \
    cr0 = MF(af[1], B##1, cr0);  ci0 = MF(af[1], B##9,  ci0); \
    cr1 = MF(af[5], B##5, cr1);  ci1 = MF(af[5], B##13, ci1); \
    cr0 = MF(af[2], B##2, cr0);  ci0 = MF(af[2], B##10, ci0); \
    cr1 = MF(af[6], B##6, cr1);  ci1 = MF(af[6], B##14, ci1); \
    cr0 = MF(af[3], B##3, cr0);  ci0 = MF(af[3], B##11, ci0); \
    cr1 = MF(af[7], B##7, cr1);  ci1 = MF(af[7], B##15, ci1); \
    const int c_ = whalf * 8 + (CC); \
    float sgn_[4]; \
    _Pragma("unroll") \
    for (int mw = 0; mw < 4; ++mw) { \
        const int scw = __builtin_popcount((c_ * 16) & TB.meas[mw]) & 1; \
        sgn_[mw] = (slm[mw] ^ scw) ? -1.f : 1.f; \
    } \
    _Pragma("unroll") \
    for (int r = 0; r < 4; ++r) { \
        const float re = cr0[r] + cr1[r], im = ci0[r] + ci1[r]; \
        const float p = re * re + im * im; \
        sS[r] += p; \
        _Pragma("unroll") \
        for (int mw = 0; mw < 4; ++mw) sq[mw][r] = fmaf(sgn_[mw], p, sq[mw][r]); \
    } \
}

// ---------------------------------------------------------------------------
// Single fused kernel, 256 blocks x 256 threads (4 waves), 3 grid barriers.
// Phase A: stage x tile; wave0 builds basis state k=blockIdx.x of W;
//          waves1-2 cf MLP (MFMA); wave3 zeroes acc slots.
// Phase B: quantum gemm, ALL 4 waves, 2-deep pipelined sc1 loads (32 in
//          flight, vmcnt(16)); partials combined via LDS atomics.
// Phase C: analytic BN1 + relu + layer2 -> z2 (LDS) + z2 stats atomics.
// Phase D: BN2 + relu + layer3 + layer4 + sigmoid -> out.
// All math verbatim from the verified version.
// ---------------------------------------------------------------------------
__global__ __launch_bounds__(256, 1) void k_fused(
        const float* __restrict__ x, const float* __restrict__ qw,
        const float* __restrict__ fW1, const float* __restrict__ fb1,
        const float* __restrict__ fW2, const float* __restrict__ fb2,
        const float* __restrict__ aW, const float* __restrict__ ab,
        const float* __restrict__ cW1, const float* __restrict__ cb1,
        const float* __restrict__ g1, const float* __restrict__ be1,
        const float* __restrict__ cW2, const float* __restrict__ cb2,
        const float* __restrict__ g2, const float* __restrict__ be2,
        const float* __restrict__ cW3, const float* __restrict__ cb3,
        const float* __restrict__ cW4, const float* __restrict__ cb4,
        _Float16* __restrict__ Wt, float* __restrict__ acc1,
        float* __restrict__ acc2, unsigned* __restrict__ bar,
        float* __restrict__ out)
{
    const int t = threadIdx.x, b = blockIdx.x;
    const int lane = t & 63, w = t >> 6;
    const int R0 = b * 32;

    __shared__ _Float16 xa[32 * XS];     // x tile, f16 (32 rows x 256)
    __shared__ float4 Us[48];            // per-gate SU(2) params
    __shared__ float cfb[32][4];         // cf (feature MLP output)
    __shared__ float hb[32][4];          // h
    __shared__ float z2b[32][16];        // z2
    __shared__ float pS[32];             // phase-B partial |amp|^2 sums
    __shared__ float pQ[4][32];          // phase-B partial signed sums
    __shared__ float sA[20];
    __shared__ float m1s[32], is1[32];
    __shared__ float sB[32];
    __shared__ float m2s[16], is2[16];

    // ======== Phase A ========
    #pragma unroll
    for (int i = 0; i < 8; ++i) {
        const int idx = i * 256 + t;
        const int row = idx >> 6, c4 = idx & 63;
        const float4 xv = ((const float4*)(x + (long)(R0 + row) * 256))[c4];
        _Float16* d = &xa[row * XS + c4 * 4];
        d[0] = (_Float16)xv.x; d[1] = (_Float16)xv.y;
        d[2] = (_Float16)xv.z; d[3] = (_Float16)xv.w;
    }
    if (t < 48) {
        const int l = t >> 3, q = t & 7;
        const float* a = qw + l * 24 + q * 3;
        const float h1 = 0.5f * a[0], h2 = 0.5f * a[1], h3 = 0.5f * a[2];
        const float c1 = cosf(h1), s1 = sinf(h1);
        const float c2 = cosf(h2), s2 = sinf(h2);
        const float c3 = cosf(h3), s3 = sinf(h3);
        const float m00r =  c1 * c2, m00i =  s1 * s2;   // (Ry*Rx) row 0
        const float m01r = -c1 * s2, m01i = -s1 * c2;
        float4 u;
        u.x = m00r * c3 + m00i * s3;  u.y = m00i * c3 - m00r * s3;  // u00 e^{-i h3}
        u.z = m01r * c3 + m01i * s3;  u.w = m01i * c3 - m01r * s3;  // u01 e^{-i h3}
        Us[t] = u;
    }
    if (t >= 192 && t < 224) {          // zero phase-B LDS partials
        const int r = t - 192;
        pS[r] = 0.f;
        pQ[0][r] = 0.f; pQ[1][r] = 0.f; pQ[2][r] = 0.f; pQ[3][r] = 0.f;
    }
    if (b < 32 && w == 3) {             // zero accumulator slots (coherent)
        const int l = t - 192;
        if (l < 20) coh_store_f(&acc1[b * 20 + l], 0.f);
        if (l < 32) coh_store_f(&acc2[b * 32 + l], 0.f);
    }
    __syncthreads();

    if (w == 0) {
        // ---- quantum operator build: basis state k = blockIdx.x (fp32 exact)
        const int k = b;
        v2f z[4];
        #pragma unroll
        for (int r = 0; r < 4; ++r) {
            z[r].x = (4 * lane + r == k) ? 1.f : 0.f;
            z[r].y = 0.f;
        }
#define GATE(L, W) { const float4 u = Us[(L) * 8 + (W)]; \
                     gate<TB.xm[L][W], TB.rm[L][W]>(z, lane, u.x, u.y, u.z, u.w); }
#define LAYER(L) GATE(L,0) GATE(L,1) GATE(L,2) GATE(L,3) GATE(L,4) GATE(L,5) GATE(L,6) GATE(L,7)
        LAYER(0) LAYER(1) LAYER(2) LAYER(3) LAYER(4) LAYER(5)
#undef LAYER
#undef GATE
        #pragma unroll
        for (int r = 0; r < 4; ++r) {
            const int i = 4 * lane + r;            // storage index
            coh_store_h(&Wt[(long)i * 256 + k],         (_Float16)z[r].x);
            coh_store_h(&Wt[(long)(256 + i) * 256 + k], (_Float16)z[r].y);
        }
    } else if (w <= 2) {
        // ---- cf MLP for m-tile (w-1): rows mt*16..+15 (R5-verified math)
        const int g = lane >> 4, col = lane & 15;
        const int mt = w - 1;
        half8 bf[8];
        #pragma unroll
        for (int kb = 0; kb < 8; ++kb)
            bf[kb] = *(const half8*)&xa[(mt * 16 + col) * XS + kb * 32 + g * 8];
        float accc[4] = {0.f, 0.f, 0.f, 0.f};
        #pragma unroll
        for (int jc = 0; jc < 4; ++jc) {
            f32x4 cv = {0.f, 0.f, 0.f, 0.f};
            #pragma unroll
            for (int kb = 0; kb < 8; ++kb) {
                const float* ap = fW1 + (long)(jc * 16 + col) * 256 + kb * 32 + g * 8;
                const float4 a0 = *(const float4*)ap;
                const float4 a1v = *(const float4*)(ap + 4);
                half8 af;
                af[0] = (_Float16)a0.x;  af[1] = (_Float16)a0.y;
                af[2] = (_Float16)a0.z;  af[3] = (_Float16)a0.w;
                af[4] = (_Float16)a1v.x; af[5] = (_Float16)a1v.y;
                af[6] = (_Float16)a1v.z; af[7] = (_Float16)a1v.w;
                cv = __builtin_amdgcn_mfma_f32_16x16x32_f16(af, bf[kb], cv, 0, 0, 0);
            }
            #pragma unroll
            for (int r = 0; r < 4; ++r) {
                const int j = jc * 16 + g * 4 + r;
                const float z = fmaxf(cv[r] + fb1[j], 0.f);
                #pragma unroll
                for (int c = 0; c < 4; ++c) accc[c] += z * fW2[c * 64 + j];
            }
        }
        #pragma unroll
        for (int c = 0; c < 4; ++c) {
            accc[c] += __shfl_xor(accc[c], 16, 64);
            accc[c] += __shfl_xor(accc[c], 32, 64);
        }
        if (g == 0) {
            cfb[mt * 16 + col][0] = tanh_fast(accc[0] + fb2[0]);
            cfb[mt * 16 + col][1] = tanh_fast(accc[1] + fb2[1]);
            cfb[mt * 16 + col][2] = tanh_fast(accc[2] + fb2[2]);
            cfb[mt * 16 + col][3] = tanh_fast(accc[3] + fb2[3]);
        }
    }

    gbar(bar, bar + 768);

    // ======== Phase B: quantum gemm, 2-deep pipelined (verified frag maps) ==
    {
        const int col = lane & 15, quad = lane >> 4;
        const int wrow = w & 1;          // row tile (rows wrow*16..+15)
        const int whalf = w >> 1;        // column half (c = whalf*8 + cc)
        half8 af[8];
        #pragma unroll
        for (int kb = 0; kb < 8; ++kb)
            af[kb] = *(const half8*)&xa[(wrow * 16 + col) * XS + kb * 32 + quad * 8];

        int slm[4];
        #pragma unroll
        for (int mw = 0; mw < 4; ++mw) slm[mw] = __popc(col & TB.meas[mw]) & 1;

        float sS[4] = {0.f, 0.f, 0.f, 0.f};
        float sq[4][4] = {{0.f}};
        // address of (c=whalf*8+cc, kb=0): Wt + col*256 + quad*8 + c*4096 (halves)
        const _Float16* pre = Wt + (long)col * 256 + quad * 8 + (long)(whalf * 8) * 4096;
        const _Float16* pim = pre + 65536;

        u32x4 BA0, BA1, BA2, BA3, BA4, BA5, BA6, BA7;
        u32x4 BA8, BA9, BA10, BA11, BA12, BA13, BA14, BA15;
        u32x4 BB0, BB1, BB2, BB3, BB4, BB5, BB6, BB7;
        u32x4 BB8, BB9, BB10, BB11, BB12, BB13, BB14, BB15;

        ISS(BA, pre,            pim);
        ISS(BB, pre + 1 * 4096, pim + 1 * 4096);
        WAIT16; CMP(BA, 0);
        ISS(BA, pre + 2 * 4096, pim + 2 * 4096);
        WAIT16; CMP(BB, 1);
        ISS(BB, pre + 3 * 4096, pim + 3 * 4096);
        WAIT16; CMP(BA, 2);
        ISS(BA, pre + 4 * 4096, pim + 4 * 4096);
        WAIT16; CMP(BB, 3);
        ISS(BB, pre + 5 * 4096, pim + 5 * 4096);
        WAIT16; CMP(BA, 4);
        ISS(BA, pre + 6 * 4096, pim + 6 * 4096);
        WAIT16; CMP(BB, 5);
        ISS(BB, pre + 7 * 4096, pim + 7 * 4096);
        WAIT16; CMP(BA, 6);
        WAIT0;  CMP(BB, 7);

        // all-reduce across the 16-lane col dimension (i-columns)
        #pragma unroll
        for (int r = 0; r < 4; ++r) {
            sS[r] += lanex<1>(sS[r]); sS[r] += lanex<2>(sS[r]);
            sS[r] += lanex<4>(sS[r]); sS[r] += lanex<8>(sS[r]);
            #pragma unroll
            for (int mw = 0; mw < 4; ++mw) {
                sq[mw][r] += lanex<1>(sq[mw][r]); sq[mw][r] += lanex<2>(sq[mw][r]);
                sq[mw][r] += lanex<4>(sq[mw][r]); sq[mw][r] += lanex<8>(sq[mw][r]);
            }
        }

        if (col == 0) {   // combine the two column-halves via LDS atomics
            #pragma unroll
            for (int r = 0; r < 4; ++r) {
                const int mloc = wrow * 16 + quad * 4 + r;
                atomicAdd(&pS[mloc], sS[r]);
                #pragma unroll
                for (int mw = 0; mw < 4; ++mw) atomicAdd(&pQ[mw][mloc], sq[mw][r]);
            }
        }
    }
    __syncthreads();
    if (t < 32) {
        const float inv = 1.0f / pS[t];            // folds AmplitudeEmbedding norm
        float qe[4];
        #pragma unroll
        for (int mw = 0; mw < 4; ++mw) qe[mw] = pQ[mw][t] * inv;
        #pragma unroll
        for (int kk = 0; kk < 4; ++kk) {
            float s = ab[kk] + cfb[t][kk];
            #pragma unroll
            for (int j = 0; j < 4; ++j) s += aW[kk * 4 + j] * qe[j];
            hb[t][kk] = s;
        }
    }
    __syncthreads();
    if (t < 20) {
        const int j = (t - 4) >> 2, kk = (t - 4) & 3;
        float v = 0.f;
        for (int rr = 0; rr < 32; ++rr)
            v += (t < 4) ? hb[rr][t] : hb[rr][j] * hb[rr][kk];
        atomicAdd(acc1 + (b & 31) * 20 + t, v);
    }

    gbar(bar + 256, bar + 1024);

    // ======== Phase C: analytic BN1 + relu + layer2 + z2 stats ========
    if (t < 20) {
        float s = 0.f;
        for (int sl = 0; sl < 32; ++sl) s += coh_load_f(&acc1[sl * 20 + t]);
        sA[t] = s;
    }
    __syncthreads();
    if (t < 32) {
        float mu[4], wv[4];
        #pragma unroll
        for (int k = 0; k < 4; ++k) mu[k] = sA[k] * INV_B;
        float m = cb1[t];
        #pragma unroll
        for (int k = 0; k < 4; ++k) { wv[k] = cW1[t * 4 + k]; m += wv[k] * mu[k]; }
        float var = 0.f;
        #pragma unroll
        for (int a2 = 0; a2 < 4; ++a2)
            #pragma unroll
            for (int b2 = 0; b2 < 4; ++b2)
                var += wv[a2] * wv[b2] * (sA[4 + a2 * 4 + b2] * INV_B - mu[a2] * mu[b2]);
        m1s[t] = m;
        is1[t] = 1.0f / sqrtf(var + 1e-5f);
    }
    __syncthreads();

    {   // 256 threads = 32 rows x 8 groups (2 z2-cols each)
        const int row = t & 31, grp = t >> 5;
        const float h0 = hb[row][0], h1 = hb[row][1], h2 = hb[row][2], h3 = hb[row][3];
        float a1[32];
        #pragma unroll
        for (int j = 0; j < 32; ++j) {
            float zz = cb1[j] + cW1[j * 4 + 0] * h0 + cW1[j * 4 + 1] * h1
                              + cW1[j * 4 + 2] * h2 + cW1[j * 4 + 3] * h3;
            a1[j] = fmaxf((zz - m1s[j]) * is1[j] * g1[j] + be1[j], 0.f);
        }
        #pragma unroll
        for (int d = 0; d < 2; ++d) {
            const int kk = grp * 2 + d;
            float s = cb2[kk];
            #pragma unroll
            for (int j = 0; j < 32; ++j) s += cW2[kk * 32 + j] * a1[j];
            z2b[row][kk] = s;
        }
    }
    __syncthreads();
    if (t < 32) {                      // z2 batch moments
        const int colz = t & 15, mode = t >> 4;
        float s = 0.f;
        for (int rr = 0; rr < 32; ++rr) {
            const float v = z2b[rr][colz];
            s += mode ? v * v : v;
        }
        atomicAdd(acc2 + (b & 31) * 32 + mode * 16 + colz, s);
    }

    gbar(bar + 512, bar + 1280);

    // ======== Phase D: BN2 + relu + layer3 + layer4 + sigmoid ========
    if (t < 32) {
        float s = 0.f;
        for (int sl = 0; sl < 32; ++sl) s += coh_load_f(&acc2[sl * 32 + t]);
        sB[t] = s;
    }
    __syncthreads();
    if (t < 16) {
        const float m = sB[t] * INV_B;
        const float var = sB[16 + t] * INV_B - m * m;
        m2s[t] = m;
        is2[t] = 1.0f / sqrtf(var + 1e-5f);
    }
    __syncthreads();
    if (t < 32) {
        float a2[16];
        #pragma unroll
        for (int k = 0; k < 16; ++k)
            a2[k] = fmaxf((z2b[t][k] - m2s[k]) * is2[k] * g2[k] + be2[k], 0.f);
        float z3[8];
        #pragma unroll
        for (int j = 0; j < 8; ++j) {
            float s = cb3[j];
            #pragma unroll
            for (int k = 0; k < 16; ++k) s += cW3[j * 16 + k] * a2[k];
            z3[j] = fmaxf(s, 0.f);
        }
        float y = cb4[0];
        #pragma unroll
        for (int j = 0; j < 8; ++j) y += cW4[j] * z3[j];
        out[R0 + t] = 1.0f / (1.0f + expf(-y));
    }
}

// ---------------------------------------------------------------------------
extern "C" void kernel_launch(void* const* d_in, const int* in_sizes, int n_in,
                              void* d_out, int out_size, void* d_ws, size_t ws_size,
                              hipStream_t stream) {
    (void)in_sizes; (void)n_in; (void)out_size; (void)ws_size;
    const float* x   = (const float*)d_in[0];
    const float* qw  = (const float*)d_in[1];
    const float* aW  = (const float*)d_in[2];
    const float* ab  = (const float*)d_in[3];
    const float* fW1 = (const float*)d_in[4];
    const float* fb1 = (const float*)d_in[5];
    const float* fW2 = (const float*)d_in[6];
    const float* fb2 = (const float*)d_in[7];
    const float* cW1 = (const float*)d_in[8];
    const float* cb1 = (const float*)d_in[9];
    const float* g1  = (const float*)d_in[10];
    const float* be1 = (const float*)d_in[11];
    const float* cW2 = (const float*)d_in[12];
    const float* cb2 = (const float*)d_in[13];
    const float* g2  = (const float*)d_in[14];
    const float* be2 = (const float*)d_in[15];
    const float* cW3 = (const float*)d_in[16];
    const float* cb3 = (const float*)d_in[17];
    const float* cW4 = (const float*)d_in[18];
    const float* cb4 = (const float*)d_in[19];

    float* ws    = (float*)d_ws;
    float* acc1  = ws;                         // 640 floats (ws[0..639])
    float* acc2  = ws + 1024;                  // 1024 floats (ws[1024..2047])
    unsigned* bar = (unsigned*)(ws + 2048);    // arr @ +0/+256/+512 (u32 idx),
                                               // rel @ +768/+1024/+1280 (16 lines each)
    _Float16* Wt = (_Float16*)(ws + 215040);   // 512 x 256 f16 = 256 KB
    float* outp  = (float*)d_out;

    hipMemsetAsync(bar, 0, 6144, stream);
    k_fused<<<256, 256, 0, stream>>>(x, qw, fW1, fb1, fW2, fb2, aW, ab,
                                     cW1, cb1, g1, be1, cW2, cb2, g2, be2,
                                     cW3, cb3, cW4, cb4, Wt, acc1, acc2, bar, outp);
}

// Round 8
// 126.946 us; speedup vs baseline: 1.3766x; 1.0435x over previous
//
#include <hip/hip_runtime.h>
#include <math.h>

#define INV_B (1.0f / 8192.0f)

typedef float  v2f  __attribute__((ext_vector_type(2)));
typedef _Float16 half8 __attribute__((ext_vector_type(8)));
typedef float  f32x4 __attribute__((ext_vector_type(4)));
typedef unsigned u32x4 __attribute__((ext_vector_type(4)));

// ---------------------------------------------------------------------------
// Compile-time GF(2) tracking of the CNOT network (R3-verified, absmax 0.0).
// Index i (8 bits): wire w <-> bit (7-w).  Storage: i = 4*lane + reg.
// ---------------------------------------------------------------------------
struct QTables {
    int xm[6][8];   // xor (partner) mask per (layer, wire)
    int rm[6][8];   // row parity mask per (layer, wire)
    int meas[4];    // measurement parity masks on storage index, wires 0..3
};
constexpr QTables make_tables() {
    QTables T{};
    int Mrow[8] = {}, Ncol[8] = {};
    for (int b = 0; b < 8; ++b) { Mrow[b] = 1 << b; Ncol[b] = 1 << b; }
    constexpr int bc[11] = {7,6,5,4,3,2,1,0,7,5,3};
    constexpr int bt[11] = {6,5,4,3,2,1,0,7,5,3,1};
    for (int l = 0; l < 6; ++l) {
        for (int w = 0; w < 8; ++w) { T.xm[l][w] = Ncol[7 - w]; T.rm[l][w] = Mrow[7 - w]; }
        for (int k = 0; k < 11; ++k) { Mrow[bt[k]] ^= Mrow[bc[k]]; Ncol[bc[k]] ^= Ncol[bt[k]]; }
    }
    for (int w = 0; w < 4; ++w) T.meas[w] = Mrow[7 - w];
    return T;
}
constexpr QTables TB = make_tables();

// xor-shuffle along lane mask ML: 1..3 DPP quad_perm (VALU pipe),
// 4..31 ds_swizzle (LDS pipe, immediate offset), >=32 shfl (bpermute).
template<int ML>
static __device__ __forceinline__ float lanex(float v) {
    if constexpr (ML == 0) { return v; }
    else if constexpr (ML == 1) { return __int_as_float(__builtin_amdgcn_update_dpp(0, __float_as_int(v), 0xB1, 0xF, 0xF, true)); }
    else if constexpr (ML == 2) { return __int_as_float(__builtin_amdgcn_update_dpp(0, __float_as_int(v), 0x4E, 0xF, 0xF, true)); }
    else if constexpr (ML == 3) { return __int_as_float(__builtin_amdgcn_update_dpp(0, __float_as_int(v), 0x1B, 0xF, 0xF, true)); }
    else if constexpr (ML < 32) { return __int_as_float(__builtin_amdgcn_ds_swizzle(__float_as_int(v), 0x1F | (ML << 10))); }
    else { return __shfl_xor(v, ML, 64); }
}

static __device__ __forceinline__ float tanh_fast(float v) {
    const float c = fminf(fmaxf(v, -10.f), 10.f);
    const float e = __expf(2.f * c);
    return (e - 1.f) / (e + 1.f);
}

// Coherent (agent-scope) helpers. All cross-block traffic is agent-coherent
// => NO L2 fences (wbl2/inv) anywhere. Proven on HW in R5/R6/R7.
static __device__ __forceinline__ void coh_store_h(_Float16* p, _Float16 v) {
    __hip_atomic_store((short*)p, __builtin_bit_cast(short, v),
                       __ATOMIC_RELAXED, __HIP_MEMORY_SCOPE_AGENT);
}
static __device__ __forceinline__ void coh_store_f(float* p, float v) {
    __hip_atomic_store(p, v, __ATOMIC_RELAXED, __HIP_MEMORY_SCOPE_AGENT);
}
static __device__ __forceinline__ float coh_load_f(const float* p) {
    return __hip_atomic_load(p, __ATOMIC_RELAXED, __HIP_MEMORY_SCOPE_AGENT);
}

// Fused SU(2) gate, packed complex (R3/R5-verified math).
template<int XM, int RM>
static __device__ __forceinline__ void gate(v2f (&z)[4], const int lane,
                                            const float u00r, const float u00i,
                                            const float u01r, const float u01i) {
    constexpr int ML = XM >> 2, MR = XM & 3;
    constexpr int RL = RM >> 2, RR = RM & 3;
    const int pl = __popc(lane & RL) & 1;
    const float csi0 = pl ? -u00i : u00i;
    const float cpr0 = pl ? -u01r : u01r;
    const float csi1 = -csi0, cpr1 = -cpr0;
    v2f p[4];
    #pragma unroll
    for (int r = 0; r < 4; ++r) {
        p[r].x = lanex<ML>(z[r ^ MR].x);
        p[r].y = lanex<ML>(z[r ^ MR].y);
    }
    #pragma unroll
    for (int r = 0; r < 4; ++r) {
        const int pb = __builtin_popcount(r & RR) & 1;
        const float csi = pb ? csi1 : csi0;
        const float cpr = pb ? cpr1 : cpr0;
        const v2f zs = { -z[r].y, z[r].x };
        const v2f ps = { -p[r].y, p[r].x };
        z[r] = ((u00r * z[r] + csi * zs) + cpr * p[r]) + u01i * ps;
    }
}

// ---------------------------------------------------------------------------
// Fence-FREE grid barrier, 16-line release fan-out (R6/R7-verified).
// ---------------------------------------------------------------------------
static __device__ __forceinline__ void gbar(unsigned* arr, unsigned* rel) {
    __syncthreads();
    if (blockIdx.x == 0) {
        if (threadIdx.x != 0) {
            while (!__hip_atomic_load(&arr[threadIdx.x], __ATOMIC_RELAXED,
                                      __HIP_MEMORY_SCOPE_AGENT))
                __builtin_amdgcn_s_sleep(2);
        }
        __syncthreads();               // all arrivals seen
        if (threadIdx.x < 16)
            __hip_atomic_store(&rel[threadIdx.x * 16], 1u, __ATOMIC_RELAXED,
                               __HIP_MEMORY_SCOPE_AGENT);
        __syncthreads();
    } else {
        if (threadIdx.x == 0) {
            __hip_atomic_store(&arr[blockIdx.x], 1u, __ATOMIC_RELAXED,
                               __HIP_MEMORY_SCOPE_AGENT);
            unsigned* myrel = rel + (blockIdx.x & 15) * 16;
            while (!__hip_atomic_load(myrel, __ATOMIC_RELAXED, __HIP_MEMORY_SCOPE_AGENT))
                __builtin_amdgcn_s_sleep(2);
        }
        __syncthreads();
    }
}

#define XS 264   // padded LDS stride in halves (528B, 16B-divisible)

// ---- Phase-B pipelined load/compute machinery (T3/T4 counted-vmcnt) -------
// ISS: one asm batch of 16 dwordx4 sc1 loads (8 re + 8 im, imm offsets
// kb*64B). WAIT16 leaves the just-issued other buffer's 16 loads in flight.
// sched_barrier(0) after each wait stops hipcc hoisting MFMAs above the
// inline-asm wait (rule #18).
#define ISS(B, pr, pi) asm volatile( \
    "global_load_dwordx4 %0, %16, off sc1\n\t" \
    "global_load_dwordx4 %1, %16, off offset:64 sc1\n\t" \
    "global_load_dwordx4 %2, %16, off offset:128 sc1\n\t" \
    "global_load_dwordx4 %3, %16, off offset:192 sc1\n\t" \
    "global_load_dwordx4 %4, %16, off offset:256 sc1\n\t" \
    "global_load_dwordx4 %5, %16, off offset:320 sc1\n\t" \
    "global_load_dwordx4 %6, %16, off offset:384 sc1\n\t" \
    "global_load_dwordx4 %7, %16, off offset:448 sc1\n\t" \
    "global_load_dwordx4 %8, %17, off sc1\n\t" \
    "global_load_dwordx4 %9, %17, off offset:64 sc1\n\t" \
    "global_load_dwordx4 %10, %17, off offset:128 sc1\n\t" \
    "global_load_dwordx4 %11, %17, off offset:192 sc1\n\t" \
    "global_load_dwordx4 %12, %17, off offset:256 sc1\n\t" \
    "global_load_dwordx4 %13, %17, off offset:320 sc1\n\t" \
    "global_load_dwordx4 %14, %17, off offset:384 sc1\n\t" \
    "global_load_dwordx4 %15, %17, off offset:448 sc1" \
    : "=&v"(B##0), "=&v"(B##1), "=&v"(B##2), "=&v"(B##3), \
      "=&v"(B##4), "=&v"(B##5), "=&v"(B##6), "=&v"(B##7), \
      "=&v"(B##8), "=&v"(B##9), "=&v"(B##10), "=&v"(B##11), \
      "=&v"(B##12), "=&v"(B##13), "=&v"(B##14), "=&v"(B##15) \
    : "v"(pr), "v"(pi) : "memory")

#define WAIT16 do { asm volatile("s_waitcnt vmcnt(16)" ::: "memory"); \
                    __builtin_amdgcn_sched_barrier(0); } while (0)
#define WAIT0  do { asm volatile("s_waitcnt vmcnt(0)" ::: "memory"); \
                    __builtin_amdgcn_sched_barrier(0); } while (0)

#define MF(A, Bv, C) __builtin_amdgcn_mfma_f32_16x16x32_f16((A), \
                        __builtin_bit_cast(half8, (Bv)), (C), 0, 0, 0)

// One (c, row-tile) computation. Per-accumulator MFMA chains identical to
// R6/R7 (cr0: kb0-3 re, ci0: kb0-3 im, cr1/ci1: kb4-7) => bit-identical
// per-chain sums. WR selects the row tile (af[WR*8+..], sS[WR], sq[WR]).
#define CMP(B, CC, WR) { \
    f32x4 cr0 = {0.f,0.f,0.f,0.f}, ci0 = {0.f,0.f,0.f,0.f}; \
    f32x4 cr1 = {0.f,0.f,0.f,0.f}, ci1 = {0.f,0.f,0.f,0.f}; \
    cr0 = MF(af[(WR)*8+0], B##0, cr0);  ci0 = MF(af[(WR)*8+0], B##8,  ci0); \
    cr1 = MF(af[(WR)*8+4], B##4, cr1);  ci1 = MF(af[(WR)*8+4], B##12, ci1); \
    cr0 = MF(af[(WR)*8+1], B##1, cr0);  ci0 = MF(af[(WR)*8+1], B##9,  ci0); \
    cr1 = MF(af[(WR)*8+5], B##5, cr1);  ci1 = MF(af[(WR)*8+5], B##13, ci1); \
    cr0 = MF(af[(WR)*8+2], B##2, cr0);  ci0 = MF(af[(WR)*8+2], B##10, ci0); \
    cr1 = MF(af[(WR)*8+6], B##6, cr1);  ci1 = MF(af[(WR)*8+6], B##14, ci1); \
    cr0 = MF(af[(WR)*8+3], B##3, cr0);  ci0 = MF(af[(WR)*8+3], B##11, ci0); \
    cr1 = MF(af[(WR)*8+7], B##7, cr1);  ci1 = MF(af[(WR)*8+7], B##15, ci1); \
    const int c_ = cbase + (CC); \
    float sgn_[4]; \
    _Pragma("unroll") \
    for (int mw = 0; mw < 4; ++mw) { \
        const int scw = __builtin_popcount((c_ * 16) & TB.meas[mw]) & 1; \
        sgn_[mw] = (slm[mw] ^ scw) ? -1.f : 1.f; \
    } \
    _Pragma("unroll") \
    for (int r = 0; r < 4; ++r) { \
        const float re = cr0[r] + cr1[r], im = ci0[r] + ci1[r]; \
        const float p = re * re + im * im; \
        sS[WR][r] += p; \
        _Pragma("unroll") \
        for (int mw = 0; mw < 4; ++mw) sq[WR][mw][r] = fmaf(sgn_[mw], p, sq[WR][mw][r]); \
    } \
}

// ---------------------------------------------------------------------------
// Single fused kernel, 256 blocks x 256 threads (4 waves), 3 grid barriers.
// Phase A: stage x tile; wave0 builds basis state k=blockIdx.x of W;
//          waves1-2 cf MLP (MFMA); wave3 zeroes acc slots.
// Phase B: quantum gemm. NEW partition: each wave owns 4 c-values x BOTH row
//          tiles, sharing one B-load stream (R7's wrow split duplicated every
//          B load; Wt fabric traffic now 256 KB/block = read exactly once).
//          2-deep pipelined sc1 loads, vmcnt(16); LDS-atomic combine (4-way).
// Phase C: analytic BN1 + relu + layer2 -> z2 (LDS) + z2 stats atomics.
// Phase D: BN2 + relu + layer3 + layer4 + sigmoid -> out.
// ---------------------------------------------------------------------------
__global__ __launch_bounds__(256, 1) void k_fused(
        const float* __restrict__ x, const float* __restrict__ qw,
        const float* __restrict__ fW1, const float* __restrict__ fb1,
        const float* __restrict__ fW2, const float* __restrict__ fb2,
        const float* __restrict__ aW, const float* __restrict__ ab,
        const float* __restrict__ cW1, const float* __restrict__ cb1,
        const float* __restrict__ g1, const float* __restrict__ be1,
        const float* __restrict__ cW2, const float* __restrict__ cb2,
        const float* __restrict__ g2, const float* __restrict__ be2,
        const float* __restrict__ cW3, const float* __restrict__ cb3,
        const float* __restrict__ cW4, const float* __restrict__ cb4,
        _Float16* __restrict__ Wt, float* __restrict__ acc1,
        float* __restrict__ acc2, unsigned* __restrict__ bar,
        float* __restrict__ out)
{
    const int t = threadIdx.x, b = blockIdx.x;
    const int lane = t & 63, w = t >> 6;
    const int R0 = b * 32;

    __shared__ _Float16 xa[32 * XS];     // x tile, f16 (32 rows x 256)
    __shared__ float4 Us[48];            // per-gate SU(2) params
    __shared__ float cfb[32][4];         // cf (feature MLP output)
    __shared__ float hb[32][4];          // h
    __shared__ float z2b[32][16];        // z2
    __shared__ float pS[32];             // phase-B partial |amp|^2 sums
    __shared__ float pQ[4][32];          // phase-B partial signed sums
    __shared__ float sA[20];
    __shared__ float m1s[32], is1[32];
    __shared__ float sB[32];
    __shared__ float m2s[16], is2[16];

    // ======== Phase A ========
    #pragma unroll
    for (int i = 0; i < 8; ++i) {
        const int idx = i * 256 + t;
        const int row = idx >> 6, c4 = idx & 63;
        const float4 xv = ((const float4*)(x + (long)(R0 + row) * 256))[c4];
        _Float16* d = &xa[row * XS + c4 * 4];
        d[0] = (_Float16)xv.x; d[1] = (_Float16)xv.y;
        d[2] = (_Float16)xv.z; d[3] = (_Float16)xv.w;
    }
    if (t < 48) {
        const int l = t >> 3, q = t & 7;
        const float* a = qw + l * 24 + q * 3;
        const float h1 = 0.5f * a[0], h2 = 0.5f * a[1], h3 = 0.5f * a[2];
        const float c1 = cosf(h1), s1 = sinf(h1);
        const float c2 = cosf(h2), s2 = sinf(h2);
        const float c3 = cosf(h3), s3 = sinf(h3);
        const float m00r =  c1 * c2, m00i =  s1 * s2;   // (Ry*Rx) row 0
        const float m01r = -c1 * s2, m01i = -s1 * c2;
        float4 u;
        u.x = m00r * c3 + m00i * s3;  u.y = m00i * c3 - m00r * s3;  // u00 e^{-i h3}
        u.z = m01r * c3 + m01i * s3;  u.w = m01i * c3 - m01r * s3;  // u01 e^{-i h3}
        Us[t] = u;
    }
    if (t >= 192 && t < 224) {          // zero phase-B LDS partials
        const int r = t - 192;
        pS[r] = 0.f;
        pQ[0][r] = 0.f; pQ[1][r] = 0.f; pQ[2][r] = 0.f; pQ[3][r] = 0.f;
    }
    if (b < 32 && w == 3) {             // zero accumulator slots (coherent)
        const int l = t - 192;
        if (l < 20) coh_store_f(&acc1[b * 20 + l], 0.f);
        if (l < 32) coh_store_f(&acc2[b * 32 + l], 0.f);
    }
    __syncthreads();

    if (w == 0) {
        // ---- quantum operator build: basis state k = blockIdx.x (fp32 exact)
        const int k = b;
        v2f z[4];
        #pragma unroll
        for (int r = 0; r < 4; ++r) {
            z[r].x = (4 * lane + r == k) ? 1.f : 0.f;
            z[r].y = 0.f;
        }
#define GATE(L, W) { const float4 u = Us[(L) * 8 + (W)]; \
                     gate<TB.xm[L][W], TB.rm[L][W]>(z, lane, u.x, u.y, u.z, u.w); }
#define LAYER(L) GATE(L,0) GATE(L,1) GATE(L,2) GATE(L,3) GATE(L,4) GATE(L,5) GATE(L,6) GATE(L,7)
        LAYER(0) LAYER(1) LAYER(2) LAYER(3) LAYER(4) LAYER(5)
#undef LAYER
#undef GATE
        #pragma unroll
        for (int r = 0; r < 4; ++r) {
            const int i = 4 * lane + r;            // storage index
            coh_store_h(&Wt[(long)i * 256 + k],         (_Float16)z[r].x);
            coh_store_h(&Wt[(long)(256 + i) * 256 + k], (_Float16)z[r].y);
        }
    } else if (w <= 2) {
        // ---- cf MLP for m-tile (w-1): rows mt*16..+15 (R5-verified math)
        const int g = lane >> 4, col = lane & 15;
        const int mt = w - 1;
        half8 bf[8];
        #pragma unroll
        for (int kb = 0; kb < 8; ++kb)
            bf[kb] = *(const half8*)&xa[(mt * 16 + col) * XS + kb * 32 + g * 8];
        float accc[4] = {0.f, 0.f, 0.f, 0.f};
        #pragma unroll
        for (int jc = 0; jc < 4; ++jc) {
            f32x4 cv = {0.f, 0.f, 0.f, 0.f};
            #pragma unroll
            for (int kb = 0; kb < 8; ++kb) {
                const float* ap = fW1 + (long)(jc * 16 + col) * 256 + kb * 32 + g * 8;
                const float4 a0 = *(const float4*)ap;
                const float4 a1v = *(const float4*)(ap + 4);
                half8 af;
                af[0] = (_Float16)a0.x;  af[1] = (_Float16)a0.y;
                af[2] = (_Float16)a0.z;  af[3] = (_Float16)a0.w;
                af[4] = (_Float16)a1v.x; af[5] = (_Float16)a1v.y;
                af[6] = (_Float16)a1v.z; af[7] = (_Float16)a1v.w;
                cv = __builtin_amdgcn_mfma_f32_16x16x32_f16(af, bf[kb], cv, 0, 0, 0);
            }
            #pragma unroll
            for (int r = 0; r < 4; ++r) {
                const int j = jc * 16 + g * 4 + r;
                const float z = fmaxf(cv[r] + fb1[j], 0.f);
                #pragma unroll
                for (int c = 0; c < 4; ++c) accc[c] += z * fW2[c * 64 + j];
            }
        }
        #pragma unroll
        for (int c = 0; c < 4; ++c) {
            accc[c] += __shfl_xor(accc[c], 16, 64);
            accc[c] += __shfl_xor(accc[c], 32, 64);
        }
        if (g == 0) {
            cfb[mt * 16 + col][0] = tanh_fast(accc[0] + fb2[0]);
            cfb[mt * 16 + col][1] = tanh_fast(accc[1] + fb2[1]);
            cfb[mt * 16 + col][2] = tanh_fast(accc[2] + fb2[2]);
            cfb[mt * 16 + col][3] = tanh_fast(accc[3] + fb2[3]);
        }
    }

    gbar(bar, bar + 768);

    // ======== Phase B: quantum gemm, one Wt pass/block (verified frag maps) =
    {
        const int col = lane & 15, quad = lane >> 4;
        const int cbase = w * 4;         // this wave's 4 c-values
        half8 af[16];                    // BOTH row tiles (wr 0: rows 0..15, wr 1: 16..31)
        #pragma unroll
        for (int wr = 0; wr < 2; ++wr)
            #pragma unroll
            for (int kb = 0; kb < 8; ++kb)
                af[wr * 8 + kb] = *(const half8*)&xa[(wr * 16 + col) * XS + kb * 32 + quad * 8];

        int slm[4];
        #pragma unroll
        for (int mw = 0; mw < 4; ++mw) slm[mw] = __popc(col & TB.meas[mw]) & 1;

        float sS[2][4] = {{0.f}};
        float sq[2][4][4] = {{{0.f}}};
        // address of (c=cbase+cc, kb=0): Wt + col*256 + quad*8 + c*4096 (halves)
        const _Float16* pre = Wt + (long)col * 256 + quad * 8 + (long)cbase * 4096;
        const _Float16* pim = pre + 65536;

        u32x4 BA0, BA1, BA2, BA3, BA4, BA5, BA6, BA7;
        u32x4 BA8, BA9, BA10, BA11, BA12, BA13, BA14, BA15;
        u32x4 BB0, BB1, BB2, BB3, BB4, BB5, BB6, BB7;
        u32x4 BB8, BB9, BB10, BB11, BB12, BB13, BB14, BB15;

        ISS(BA, pre,            pim);
        ISS(BB, pre + 1 * 4096, pim + 1 * 4096);
        WAIT16; CMP(BA, 0, 0); CMP(BA, 0, 1);
        ISS(BA, pre + 2 * 4096, pim + 2 * 4096);
        WAIT16; CMP(BB, 1, 0); CMP(BB, 1, 1);
        ISS(BB, pre + 3 * 4096, pim + 3 * 4096);
        WAIT16; CMP(BA, 2, 0); CMP(BA, 2, 1);
        WAIT0;  CMP(BB, 3, 0); CMP(BB, 3, 1);

        // all-reduce across the 16-lane col dimension (i-columns)
        #pragma unroll
        for (int wr = 0; wr < 2; ++wr)
            #pragma unroll
            for (int r = 0; r < 4; ++r) {
                sS[wr][r] += lanex<1>(sS[wr][r]); sS[wr][r] += lanex<2>(sS[wr][r]);
                sS[wr][r] += lanex<4>(sS[wr][r]); sS[wr][r] += lanex<8>(sS[wr][r]);
                #pragma unroll
                for (int mw = 0; mw < 4; ++mw) {
                    sq[wr][mw][r] += lanex<1>(sq[wr][mw][r]);
                    sq[wr][mw][r] += lanex<2>(sq[wr][mw][r]);
                    sq[wr][mw][r] += lanex<4>(sq[wr][mw][r]);
                    sq[wr][mw][r] += lanex<8>(sq[wr][mw][r]);
                }
            }

        if (col == 0) {   // combine the four c-quarters via LDS atomics
            #pragma unroll
            for (int wr = 0; wr < 2; ++wr)
                #pragma unroll
                for (int r = 0; r < 4; ++r) {
                    const int mloc = wr * 16 + quad * 4 + r;
                    atomicAdd(&pS[mloc], sS[wr][r]);
                    #pragma unroll
                    for (int mw = 0; mw < 4; ++mw) atomicAdd(&pQ[mw][mloc], sq[wr][mw][r]);
                }
        }
    }
    __syncthreads();
    if (t < 32) {
        const float inv = 1.0f / pS[t];            // folds AmplitudeEmbedding norm
        float qe[4];
        #pragma unroll
        for (int mw = 0; mw < 4; ++mw) qe[mw] = pQ[mw][t] * inv;
        #pragma unroll
        for (int kk = 0; kk < 4; ++kk) {
            float s = ab[kk] + cfb[t][kk];
            #pragma unroll
            for (int j = 0; j < 4; ++j) s += aW[kk * 4 + j] * qe[j];
            hb[t][kk] = s;
        }
    }
    __syncthreads();
    if (t < 20) {
        const int j = (t - 4) >> 2, kk = (t - 4) & 3;
        float v = 0.f;
        for (int rr = 0; rr < 32; ++rr)
            v += (t < 4) ? hb[rr][t] : hb[rr][j] * hb[rr][kk];
        atomicAdd(acc1 + (b & 31) * 20 + t, v);
    }

    gbar(bar + 256, bar + 1024);

    // ======== Phase C: analytic BN1 + relu + layer2 + z2 stats ========
    if (t < 20) {
        float s = 0.f;
        for (int sl = 0; sl < 32; ++sl) s += coh_load_f(&acc1[sl * 20 + t]);
        sA[t] = s;
    }
    __syncthreads();
    if (t < 32) {
        float mu[4], wv[4];
        #pragma unroll
        for (int k = 0; k < 4; ++k) mu[k] = sA[k] * INV_B;
        float m = cb1[t];
        #pragma unroll
        for (int k = 0; k < 4; ++k) { wv[k] = cW1[t * 4 + k]; m += wv[k] * mu[k]; }
        float var = 0.f;
        #pragma unroll
        for (int a2 = 0; a2 < 4; ++a2)
            #pragma unroll
            for (int b2 = 0; b2 < 4; ++b2)
                var += wv[a2] * wv[b2] * (sA[4 + a2 * 4 + b2] * INV_B - mu[a2] * mu[b2]);
        m1s[t] = m;
        is1[t] = 1.0f / sqrtf(var + 1e-5f);
    }
    __syncthreads();

    {   // 256 threads = 32 rows x 8 groups (2 z2-cols each)
        const int row = t & 31, grp = t >> 5;
        const float h0 = hb[row][0], h1 = hb[row][1], h2 = hb[row][2], h3 = hb[row][3];
        float a1[32];
        #pragma unroll
        for (int j = 0; j < 32; ++j) {
            float zz = cb1[j] + cW1[j * 4 + 0] * h0 + cW1[j * 4 + 1] * h1
                              + cW1[j * 4 + 2] * h2 + cW1[j * 4 + 3] * h3;
            a1[j] = fmaxf((zz - m1s[j]) * is1[j] * g1[j] + be1[j], 0.f);
        }
        #pragma unroll
        for (int d = 0; d < 2; ++d) {
            const int kk = grp * 2 + d;
            float s = cb2[kk];
            #pragma unroll
            for (int j = 0; j < 32; ++j) s += cW2[kk * 32 + j] * a1[j];
            z2b[row][kk] = s;
        }
    }
    __syncthreads();
    if (t < 32) {                      // z2 batch moments
        const int colz = t & 15, mode = t >> 4;
        float s = 0.f;
        for (int rr = 0; rr < 32; ++rr) {
            const float v = z2b[rr][colz];
            s += mode ? v * v : v;
        }
        atomicAdd(acc2 + (b & 31) * 32 + mode * 16 + colz, s);
    }

    gbar(bar + 512, bar + 1280);

    // ======== Phase D: BN2 + relu + layer3 + layer4 + sigmoid ========
    if (t < 32) {
        float s = 0.f;
        for (int sl = 0; sl < 32; ++sl) s += coh_load_f(&acc2[sl * 32 + t]);
        sB[t] = s;
    }
    __syncthreads();
    if (t < 16) {
        const float m = sB[t] * INV_B;
        const float var = sB[16 + t] * INV_B - m * m;
        m2s[t] = m;
        is2[t] = 1.0f / sqrtf(var + 1e-5f);
    }
    __syncthreads();
    if (t < 32) {
        float a2[16];
        #pragma unroll
        for (int k = 0; k < 16; ++k)
            a2[k] = fmaxf((z2b[t][k] - m2s[k]) * is2[k] * g2[k] + be2[k], 0.f);
        float z3[8];
        #pragma unroll
        for (int j = 0; j < 8; ++j) {
            float s = cb3[j];
            #pragma unroll
            for (int k = 0; k < 16; ++k) s += cW3[j * 16 + k] * a2[k];
            z3[j] = fmaxf(s, 0.f);
        }
        float y = cb4[0];
        #pragma unroll
        for (int j = 0; j < 8; ++j) y += cW4[j] * z3[j];
        out[R0 + t] = 1.0f / (1.0f + expf(-y));
    }
}

// ---------------------------------------------------------------------------
extern "C" void kernel_launch(void* const* d_in, const int* in_sizes, int n_in,
                              void* d_out, int out_size, void* d_ws, size_t ws_size,
                              hipStream_t stream) {
    (void)in_sizes; (void)n_in; (void)out_size; (void)ws_size;
    const float* x   = (const float*)d_in[0];
    const float* qw  = (const float*)d_in[1];
    const float* aW  = (const float*)d_in[2];
    const float* ab  = (const float*)d_in[3];
    const float* fW1 = (const float*)d_in[4];
    const float* fb1 = (const float*)d_in[5];
    const float* fW2 = (const float*)d_in[6];
    const float* fb2 = (const float*)d_in[7];
    const float* cW1 = (const float*)d_in[8];
    const float* cb1 = (const float*)d_in[9];
    const float* g1  = (const float*)d_in[10];
    const float* be1 = (const float*)d_in[11];
    const float* cW2 = (const float*)d_in[12];
    const float* cb2 = (const float*)d_in[13];
    const float* g2  = (const float*)d_in[14];
    const float* be2 = (const float*)d_in[15];
    const float* cW3 = (const float*)d_in[16];
    const float* cb3 = (const float*)d_in[17];
    const float* cW4 = (const float*)d_in[18];
    const float* cb4 = (const float*)d_in[19];

    float* ws    = (float*)d_ws;
    float* acc1  = ws;                         // 640 floats (ws[0..639])
    float* acc2  = ws + 1024;                  // 1024 floats (ws[1024..2047])
    unsigned* bar = (unsigned*)(ws + 2048);    // arr @ +0/+256/+512 (u32 idx),
                                               // rel @ +768/+1024/+1280 (16 lines each)
    _Float16* Wt = (_Float16*)(ws + 215040);   // 512 x 256 f16 = 256 KB
    float* outp  = (float*)d_out;

    hipMemsetAsync(bar, 0, 6144, stream);
    k_fused<<<256, 256, 0, stream>>>(x, qw, fW1, fb1, fW2, fb2, aW, ab,
                                     cW1, cb1, g1, be1, cW2, cb2, g2, be2,
                                     cW3, cb3, cW4, cb4, Wt, acc1, acc2, bar, outp);
}